// Round 1
// baseline (3801.891 us; speedup 1.0000x reference)
//
#include <hip/hip_runtime.h>
#include <math.h>

// ---------------------------------------------------------------------------
// GNN: 3x GatedGraphConv (C=32,64,128; 4 inner layers each) + BN + pool + MLP
// fp32 vector implementation, round 1 (correctness + reasonable tiling).
// ---------------------------------------------------------------------------

#define EPS_BN 1e-5f

__device__ __forceinline__ float elu_f(float v) {
    return v > 0.f ? v : expm1f(v);
}
__device__ __forceinline__ float sigmoid_f(float v) {
    return 1.f / (1.f + expf(-v));
}

// wT[k*rows + j] = w[j*cols + k]   (w: [rows, cols])
__global__ __launch_bounds__(256) void transpose_w_kernel(
    const float* __restrict__ w, float* __restrict__ wT, int rows, int cols) {
    int t = blockIdx.x * 256 + threadIdx.x;
    if (t < rows * cols) {
        int j = t / cols, k = t % cols;
        wT[k * rows + j] = w[t];
    }
}

// M = X @ W  (X: [N,C], W: [C,C] row-major k-major) ; also zero AGG
template <int C>
__global__ __launch_bounds__(256) void matmul_zero_kernel(
    const float* __restrict__ X, const float* __restrict__ W,
    float* __restrict__ M, float* __restrict__ AGG, int N) {
    constexpr int BN = 2048 / C;     // nodes per block
    constexpr int NPT = 8;           // (node,c) pairs per thread
    constexpr int NSTEP = 256 / C;   // node stride between pairs
    __shared__ float Xs[2048];
    int tid = threadIdx.x;
    int node0 = blockIdx.x * BN;
    for (int i = tid; i < 2048; i += 256) {
        int n = node0 + i / C;
        Xs[i] = (n < N) ? X[(size_t)n * C + (i & (C - 1))] : 0.f;
    }
    __syncthreads();
    int c = tid & (C - 1);
    int nlb = tid / C;
    float acc[NPT];
#pragma unroll
    for (int i = 0; i < NPT; ++i) acc[i] = 0.f;
    for (int k = 0; k < C; ++k) {
        float w = W[k * C + c];
#pragma unroll
        for (int i = 0; i < NPT; ++i) {
            acc[i] += Xs[(nlb + i * NSTEP) * C + k] * w;
        }
    }
#pragma unroll
    for (int i = 0; i < NPT; ++i) {
        int n = node0 + nlb + i * NSTEP;
        if (n < N) {
            M[(size_t)n * C + c] = acc[i];
            AGG[(size_t)n * C + c] = 0.f;
        }
    }
}

// AGG[dst] += M[src] over all edges
template <int C>
__global__ __launch_bounds__(256) void scatter_kernel(
    const float* __restrict__ M, const int* __restrict__ ei,
    float* __restrict__ AGG, int E) {
    long total = (long)E * C;
    long stride = (long)gridDim.x * 256;
    for (long t = (long)blockIdx.x * 256 + threadIdx.x; t < total; t += stride) {
        int e = (int)(t / C);
        int c = (int)(t & (C - 1));
        int s = ei[e];
        int d = ei[E + e];
        atomicAdd(&AGG[(size_t)d * C + c], M[(size_t)s * C + c]);
    }
}

// Fused GRUCell: X = GRU(AGG, X)   (in-place on X)
// wiT/whT: [C, 3C] (transposed), bi/bh: [3C]
template <int C>
__global__ __launch_bounds__(256) void gru_kernel(
    float* __restrict__ X, const float* __restrict__ AGG,
    const float* __restrict__ wiT, const float* __restrict__ whT,
    const float* __restrict__ bi, const float* __restrict__ bh, int N) {
    constexpr int BN = 2048 / C;
    constexpr int NPT = 8;
    constexpr int NSTEP = 256 / C;
    __shared__ float Xs[2048];
    __shared__ float As[2048];
    int tid = threadIdx.x;
    int node0 = blockIdx.x * BN;
    for (int i = tid; i < 2048; i += 256) {
        int n = node0 + i / C;
        size_t gi = (size_t)n * C + (i & (C - 1));
        Xs[i] = (n < N) ? X[gi] : 0.f;
        As[i] = (n < N) ? AGG[gi] : 0.f;
    }
    __syncthreads();
    int c = tid & (C - 1);
    int nlb = tid / C;
    float ir[NPT], iz[NPT], inn[NPT], hr[NPT], hz[NPT], hn[NPT];
#pragma unroll
    for (int i = 0; i < NPT; ++i) {
        ir[i] = iz[i] = inn[i] = hr[i] = hz[i] = hn[i] = 0.f;
    }
    for (int k = 0; k < C; ++k) {
        const float* wi = &wiT[k * 3 * C];
        const float* wh = &whT[k * 3 * C];
        float wir = wi[c], wiz = wi[C + c], win = wi[2 * C + c];
        float whr = wh[c], whz = wh[C + c], whn = wh[2 * C + c];
#pragma unroll
        for (int i = 0; i < NPT; ++i) {
            int nl = nlb + i * NSTEP;
            float a = As[nl * C + k];
            float xv = Xs[nl * C + k];
            ir[i] += a * wir;
            iz[i] += a * wiz;
            inn[i] += a * win;
            hr[i] += xv * whr;
            hz[i] += xv * whz;
            hn[i] += xv * whn;
        }
    }
    float bir = bi[c], biz = bi[C + c], bin = bi[2 * C + c];
    float bhr = bh[c], bhz = bh[C + c], bhn = bh[2 * C + c];
#pragma unroll
    for (int i = 0; i < NPT; ++i) {
        int nl = nlb + i * NSTEP;
        int n = node0 + nl;
        if (n < N) {
            float r = sigmoid_f(ir[i] + bir + hr[i] + bhr);
            float z = sigmoid_f(iz[i] + biz + hz[i] + bhz);
            float nn = tanhf(inn[i] + bin + r * (hn[i] + bhn));
            float xo = Xs[nl * C + c];
            X[(size_t)n * C + c] = (1.f - z) * nn + z * xo;
        }
    }
}

// Xout[n, 0:Cin] = bn(elu(Xin[n, :])), Xout[n, Cin:Cout] = 0
template <int Cin, int Cout>
__global__ __launch_bounds__(256) void elu_bn_pad_kernel(
    const float* __restrict__ Xin, float* __restrict__ Xout,
    const float* __restrict__ gamma, const float* __restrict__ beta,
    const float* __restrict__ mean, const float* __restrict__ var, int N) {
    long t = (long)blockIdx.x * 256 + threadIdx.x;
    long total = (long)N * Cout;
    if (t >= total) return;
    int n = (int)(t / Cout);
    int c = (int)(t & (Cout - 1));
    float v = 0.f;
    if (c < Cin) {
        float x = Xin[(size_t)n * Cin + c];
        x = elu_f(x);
        v = (x - mean[c]) * rsqrtf(var[c] + EPS_BN) * gamma[c] + beta[c];
    }
    Xout[t] = v;
}

// G[batch[n]] += elu(X[n])   (C=128)
__global__ __launch_bounds__(256) void pool_elu_kernel(
    const float* __restrict__ X, const int* __restrict__ batch,
    float* __restrict__ G, int N) {
    long t = (long)blockIdx.x * 256 + threadIdx.x;
    if (t >= (long)N * 128) return;
    int n = (int)(t >> 7);
    int c = (int)(t & 127);
    float v = elu_f(X[t]);
    atomicAdd(&G[batch[n] * 128 + c], v);
}

// G2[g, j] = elu(b[j] + G[g,:] . W[j,:])   W: [256,128]
__global__ __launch_bounds__(256) void fc1_kernel(
    const float* __restrict__ G, const float* __restrict__ W,
    const float* __restrict__ b, float* __restrict__ G2) {
    __shared__ float row[128];
    int g = blockIdx.x;
    int j = threadIdx.x;
    if (j < 128) row[j] = G[g * 128 + j];
    __syncthreads();
    float acc = b[j];
    for (int k = 0; k < 128; ++k) acc += row[k] * W[j * 128 + k];
    G2[g * 256 + j] = elu_f(acc);
}

// out[g, :] = log_softmax(b + G2[g,:] @ W.T)   W: [10,256]
__global__ __launch_bounds__(64) void fc2_logsoftmax_kernel(
    const float* __restrict__ G2, const float* __restrict__ W,
    const float* __restrict__ b, float* __restrict__ out) {
    __shared__ float row[256];
    __shared__ float logits[10];
    __shared__ float red[2];
    int g = blockIdx.x;
    int tid = threadIdx.x;
    for (int i = tid; i < 256; i += 64) row[i] = G2[g * 256 + i];
    __syncthreads();
    if (tid < 10) {
        float acc = b[tid];
        for (int k = 0; k < 256; ++k) acc += row[k] * W[tid * 256 + k];
        logits[tid] = acc;
    }
    __syncthreads();
    if (tid == 0) {
        float m = -1e30f;
        for (int a = 0; a < 10; ++a) m = fmaxf(m, logits[a]);
        float s = 0.f;
        for (int a = 0; a < 10; ++a) s += expf(logits[a] - m);
        red[0] = m;
        red[1] = logf(s);
    }
    __syncthreads();
    if (tid < 10) out[g * 10 + tid] = logits[tid] - red[0] - red[1];
}

// ---------------------------------------------------------------------------

template <int C>
static void run_conv(float* X, float* M, float* AGG, float* WIT, float* WHT,
                     const float* W, const float* wih, const float* whh,
                     const float* bih, const float* bhh, const int* ei,
                     int N, int E, hipStream_t stream) {
    int wt_threads = 3 * C * C;
    int wt_blocks = (wt_threads + 255) / 256;
    transpose_w_kernel<<<wt_blocks, 256, 0, stream>>>(wih, WIT, 3 * C, C);
    transpose_w_kernel<<<wt_blocks, 256, 0, stream>>>(whh, WHT, 3 * C, C);
    constexpr int BN = 2048 / C;
    int blocks = (N + BN - 1) / BN;
    long total = (long)E * C;
    int sblocks = (int)((total + 1023) / 1024);
    for (int it = 0; it < 4; ++it) {
        matmul_zero_kernel<C><<<blocks, 256, 0, stream>>>(X, W + (size_t)it * C * C, M, AGG, N);
        scatter_kernel<C><<<sblocks, 256, 0, stream>>>(M, ei, AGG, E);
        gru_kernel<C><<<blocks, 256, 0, stream>>>(X, AGG, WIT, WHT, bih, bhh, N);
    }
}

extern "C" void kernel_launch(void* const* d_in, const int* in_sizes, int n_in,
                              void* d_out, int out_size, void* d_ws, size_t ws_size,
                              hipStream_t stream) {
    const float* x = (const float*)d_in[0];
    const int* ei = (const int*)d_in[1];
    const int* batch = (const int*)d_in[2];
    const float* fc1W = (const float*)d_in[3];
    const float* fc1b = (const float*)d_in[4];
    const float* fc2W = (const float*)d_in[5];
    const float* fc2b = (const float*)d_in[6];
    const float* c1W = (const float*)d_in[7];
    const float* c1wih = (const float*)d_in[8];
    const float* c1whh = (const float*)d_in[9];
    const float* c1bih = (const float*)d_in[10];
    const float* c1bhh = (const float*)d_in[11];
    const float* c2W = (const float*)d_in[12];
    const float* c2wih = (const float*)d_in[13];
    const float* c2whh = (const float*)d_in[14];
    const float* c2bih = (const float*)d_in[15];
    const float* c2bhh = (const float*)d_in[16];
    const float* c3W = (const float*)d_in[17];
    const float* c3wih = (const float*)d_in[18];
    const float* c3whh = (const float*)d_in[19];
    const float* c3bih = (const float*)d_in[20];
    const float* c3bhh = (const float*)d_in[21];
    const float* bn1g = (const float*)d_in[22];
    const float* bn1b = (const float*)d_in[23];
    const float* bn1m = (const float*)d_in[24];
    const float* bn1v = (const float*)d_in[25];
    const float* bn2g = (const float*)d_in[26];
    const float* bn2b = (const float*)d_in[27];
    const float* bn2m = (const float*)d_in[28];
    const float* bn2v = (const float*)d_in[29];

    int N = in_sizes[0] / 32;
    int E = in_sizes[1] / 2;

    const size_t NODE_BUF = (size_t)N * 128;  // 6.4M floats
    float* B0 = (float*)d_ws;
    float* B1 = B0 + NODE_BUF;
    float* B2 = B1 + NODE_BUF;
    float* WIT = B2 + NODE_BUF;     // up to 3*128*128 = 49152
    float* WHT = WIT + 49152;
    float* G = WHT + 49152;         // 256*128
    float* G2 = G + 32768;          // 256*256

    // x -> B0 (conv1 state, [N,32])
    hipMemcpyAsync(B0, x, (size_t)N * 32 * sizeof(float),
                   hipMemcpyDeviceToDevice, stream);

    // conv1 (C=32): X=B0, M=B1, AGG=B2
    run_conv<32>(B0, B1, B2, WIT, WHT, c1W, c1wih, c1whh, c1bih, c1bhh, ei, N, E, stream);
    {
        long total = (long)N * 64;
        int blocks = (int)((total + 255) / 256);
        elu_bn_pad_kernel<32, 64><<<blocks, 256, 0, stream>>>(B0, B1, bn1g, bn1b, bn1m, bn1v, N);
    }

    // conv2 (C=64): X=B1, M=B0, AGG=B2
    run_conv<64>(B1, B0, B2, WIT, WHT, c2W, c2wih, c2whh, c2bih, c2bhh, ei, N, E, stream);
    {
        long total = (long)N * 128;
        int blocks = (int)((total + 255) / 256);
        elu_bn_pad_kernel<64, 128><<<blocks, 256, 0, stream>>>(B1, B0, bn2g, bn2b, bn2m, bn2v, N);
    }

    // conv3 (C=128): X=B0, M=B1, AGG=B2
    run_conv<128>(B0, B1, B2, WIT, WHT, c3W, c3wih, c3whh, c3bih, c3bhh, ei, N, E, stream);

    // pool: G[g] = sum over nodes of elu(B0[n])
    hipMemsetAsync(G, 0, 256 * 128 * sizeof(float), stream);
    {
        long total = (long)N * 128;
        int blocks = (int)((total + 255) / 256);
        pool_elu_kernel<<<blocks, 256, 0, stream>>>(B0, batch, G, N);
    }

    // fc1 + elu
    fc1_kernel<<<256, 256, 0, stream>>>(G, fc1W, fc1b, G2);
    // fc2 + log_softmax
    fc2_logsoftmax_kernel<<<256, 64, 0, stream>>>(G2, fc2W, fc2b, (float*)d_out);
}

// Round 2
// 2066.372 us; speedup vs baseline: 1.8399x; 1.8399x over previous
//
#include <hip/hip_runtime.h>
#include <math.h>

// ---------------------------------------------------------------------------
// GNN: 3x GatedGraphConv (C=32,64,128; 4 inner layers each) + BN + pool + MLP
// Round 2: replace edge scatter-atomics with CSR-by-dst gather (edge list is
// static across all 12 propagation steps -> build CSR once per launch).
// ---------------------------------------------------------------------------

#define EPS_BN 1e-5f

__device__ __forceinline__ float elu_f(float v) {
    return v > 0.f ? v : expm1f(v);
}
__device__ __forceinline__ float sigmoid_f(float v) {
    return 1.f / (1.f + expf(-v));
}

// ------------------------- CSR construction -------------------------------

__global__ __launch_bounds__(256) void hist_kernel(
    const int* __restrict__ ei, int* __restrict__ deg, int E) {
    int e = blockIdx.x * 256 + threadIdx.x;
    if (e < E) atomicAdd(&deg[ei[E + e]], 1);
}

// per-block (1024 elems) exclusive scan; blockSums[b] = block total
__global__ __launch_bounds__(256) void scan1_kernel(
    const int* __restrict__ deg, int* __restrict__ out,
    int* __restrict__ blockSums, int N) {
    __shared__ int sdata[256];
    int b = blockIdx.x, t = threadIdx.x;
    int base = b * 1024 + t * 4;
    int v[4], s = 0;
#pragma unroll
    for (int i = 0; i < 4; ++i) {
        v[i] = (base + i < N) ? deg[base + i] : 0;
        s += v[i];
    }
    sdata[t] = s;
    __syncthreads();
    for (int off = 1; off < 256; off <<= 1) {
        int x = (t >= off) ? sdata[t - off] : 0;
        __syncthreads();
        sdata[t] += x;
        __syncthreads();
    }
    int run = sdata[t] - s;  // exclusive prefix of this thread within block
#pragma unroll
    for (int i = 0; i < 4; ++i) {
        if (base + i < N) out[base + i] = run;
        run += v[i];
    }
    if (t == 255) blockSums[b] = sdata[255];
}

__global__ void scan2_kernel(int* blockSums, int nb) {
    if (threadIdx.x == 0 && blockIdx.x == 0) {
        int run = 0;
        for (int i = 0; i < nb; ++i) {
            int v = blockSums[i];
            blockSums[i] = run;
            run += v;
        }
    }
}

__global__ __launch_bounds__(256) void scan3_kernel(
    const int* __restrict__ out, const int* __restrict__ blockSums,
    int* __restrict__ rowstart, int* __restrict__ writeptr, int N, int E) {
    int i = blockIdx.x * 256 + threadIdx.x;
    if (i < N) {
        int v = out[i] + blockSums[i >> 10];
        rowstart[i] = v;
        writeptr[i] = v;
    }
    if (i == 0) rowstart[N] = E;
}

__global__ __launch_bounds__(256) void fill_kernel(
    const int* __restrict__ ei, int* __restrict__ writeptr,
    int* __restrict__ csr_src, int E) {
    int e = blockIdx.x * 256 + threadIdx.x;
    if (e < E) {
        int d = ei[E + e];
        int p = atomicAdd(&writeptr[d], 1);
        csr_src[p] = ei[e];
    }
}

// ------------------------- weight transpose -------------------------------

__global__ __launch_bounds__(256) void transpose_w_kernel(
    const float* __restrict__ w, float* __restrict__ wT, int rows, int cols) {
    int t = blockIdx.x * 256 + threadIdx.x;
    if (t < rows * cols) {
        int j = t / cols, k = t % cols;
        wT[k * rows + j] = w[t];
    }
}

// ------------------------- M = X @ W --------------------------------------

template <int C>
__global__ __launch_bounds__(256) void matmul_kernel(
    const float* __restrict__ X, const float* __restrict__ W,
    float* __restrict__ M, int N) {
    constexpr int BN = 2048 / C;
    constexpr int NPT = 8;
    constexpr int NSTEP = 256 / C;
    __shared__ float Xs[2048];
    int tid = threadIdx.x;
    int node0 = blockIdx.x * BN;
    for (int i = tid; i < 2048; i += 256) {
        int n = node0 + i / C;
        Xs[i] = (n < N) ? X[(size_t)n * C + (i & (C - 1))] : 0.f;
    }
    __syncthreads();
    int c = tid & (C - 1);
    int nlb = tid / C;
    float acc[NPT];
#pragma unroll
    for (int i = 0; i < NPT; ++i) acc[i] = 0.f;
    for (int k = 0; k < C; ++k) {
        float w = W[k * C + c];
#pragma unroll
        for (int i = 0; i < NPT; ++i) {
            acc[i] += Xs[(nlb + i * NSTEP) * C + k] * w;
        }
    }
#pragma unroll
    for (int i = 0; i < NPT; ++i) {
        int n = node0 + nlb + i * NSTEP;
        if (n < N) M[(size_t)n * C + c] = acc[i];
    }
}

// ------------------------- AGG[d] = sum_{e: dst=d} M[src[e]] --------------

template <int C>
__global__ __launch_bounds__(256) void gather_kernel(
    const float* __restrict__ M, const int* __restrict__ rowstart,
    const int* __restrict__ csr_src, float* __restrict__ AGG, int N) {
    constexpr int LPG = C / 4;        // lanes per dst node (float4 each)
    constexpr int GPB = 256 / LPG;    // dst nodes per block
    int lane = threadIdx.x % LPG;
    int grp = threadIdx.x / LPG;
    int d = blockIdx.x * GPB + grp;
    if (d >= N) return;
    int p = rowstart[d];
    int p1 = rowstart[d + 1];
    float4 acc = {0.f, 0.f, 0.f, 0.f};
    for (; p < p1; ++p) {
        int s = csr_src[p];
        float4 v = ((const float4*)&M[(size_t)s * C])[lane];
        acc.x += v.x;
        acc.y += v.y;
        acc.z += v.z;
        acc.w += v.w;
    }
    ((float4*)&AGG[(size_t)d * C])[lane] = acc;
}

// ------------------------- GRU cell ---------------------------------------

template <int C>
__global__ __launch_bounds__(256) void gru_kernel(
    float* __restrict__ X, const float* __restrict__ AGG,
    const float* __restrict__ wiT, const float* __restrict__ whT,
    const float* __restrict__ bi, const float* __restrict__ bh, int N) {
    constexpr int BN = 2048 / C;
    constexpr int NPT = 8;
    constexpr int NSTEP = 256 / C;
    __shared__ float Xs[2048];
    __shared__ float As[2048];
    int tid = threadIdx.x;
    int node0 = blockIdx.x * BN;
    for (int i = tid; i < 2048; i += 256) {
        int n = node0 + i / C;
        size_t gi = (size_t)n * C + (i & (C - 1));
        Xs[i] = (n < N) ? X[gi] : 0.f;
        As[i] = (n < N) ? AGG[gi] : 0.f;
    }
    __syncthreads();
    int c = tid & (C - 1);
    int nlb = tid / C;
    float ir[NPT], iz[NPT], inn[NPT], hr[NPT], hz[NPT], hn[NPT];
#pragma unroll
    for (int i = 0; i < NPT; ++i) {
        ir[i] = iz[i] = inn[i] = hr[i] = hz[i] = hn[i] = 0.f;
    }
    for (int k = 0; k < C; ++k) {
        const float* wi = &wiT[k * 3 * C];
        const float* wh = &whT[k * 3 * C];
        float wir = wi[c], wiz = wi[C + c], win = wi[2 * C + c];
        float whr = wh[c], whz = wh[C + c], whn = wh[2 * C + c];
#pragma unroll
        for (int i = 0; i < NPT; ++i) {
            int nl = nlb + i * NSTEP;
            float a = As[nl * C + k];
            float xv = Xs[nl * C + k];
            ir[i] += a * wir;
            iz[i] += a * wiz;
            inn[i] += a * win;
            hr[i] += xv * whr;
            hz[i] += xv * whz;
            hn[i] += xv * whn;
        }
    }
    float bir = bi[c], biz = bi[C + c], bin = bi[2 * C + c];
    float bhr = bh[c], bhz = bh[C + c], bhn = bh[2 * C + c];
#pragma unroll
    for (int i = 0; i < NPT; ++i) {
        int nl = nlb + i * NSTEP;
        int n = node0 + nl;
        if (n < N) {
            float r = sigmoid_f(ir[i] + bir + hr[i] + bhr);
            float z = sigmoid_f(iz[i] + biz + hz[i] + bhz);
            float nn = tanhf(inn[i] + bin + r * (hn[i] + bhn));
            float xo = Xs[nl * C + c];
            X[(size_t)n * C + c] = (1.f - z) * nn + z * xo;
        }
    }
}

// ------------------------- epilogues --------------------------------------

template <int Cin, int Cout>
__global__ __launch_bounds__(256) void elu_bn_pad_kernel(
    const float* __restrict__ Xin, float* __restrict__ Xout,
    const float* __restrict__ gamma, const float* __restrict__ beta,
    const float* __restrict__ mean, const float* __restrict__ var, int N) {
    long t = (long)blockIdx.x * 256 + threadIdx.x;
    long total = (long)N * Cout;
    if (t >= total) return;
    int n = (int)(t / Cout);
    int c = (int)(t & (Cout - 1));
    float v = 0.f;
    if (c < Cin) {
        float x = Xin[(size_t)n * Cin + c];
        x = elu_f(x);
        v = (x - mean[c]) * rsqrtf(var[c] + EPS_BN) * gamma[c] + beta[c];
    }
    Xout[t] = v;
}

__global__ __launch_bounds__(256) void pool_elu_kernel(
    const float* __restrict__ X, const int* __restrict__ batch,
    float* __restrict__ G, int N) {
    long t = (long)blockIdx.x * 256 + threadIdx.x;
    if (t >= (long)N * 128) return;
    int n = (int)(t >> 7);
    int c = (int)(t & 127);
    float v = elu_f(X[t]);
    atomicAdd(&G[batch[n] * 128 + c], v);
}

__global__ __launch_bounds__(256) void fc1_kernel(
    const float* __restrict__ G, const float* __restrict__ W,
    const float* __restrict__ b, float* __restrict__ G2) {
    __shared__ float row[128];
    int g = blockIdx.x;
    int j = threadIdx.x;
    if (j < 128) row[j] = G[g * 128 + j];
    __syncthreads();
    float acc = b[j];
    for (int k = 0; k < 128; ++k) acc += row[k] * W[j * 128 + k];
    G2[g * 256 + j] = elu_f(acc);
}

__global__ __launch_bounds__(64) void fc2_logsoftmax_kernel(
    const float* __restrict__ G2, const float* __restrict__ W,
    const float* __restrict__ b, float* __restrict__ out) {
    __shared__ float row[256];
    __shared__ float logits[10];
    __shared__ float red[2];
    int g = blockIdx.x;
    int tid = threadIdx.x;
    for (int i = tid; i < 256; i += 64) row[i] = G2[g * 256 + i];
    __syncthreads();
    if (tid < 10) {
        float acc = b[tid];
        for (int k = 0; k < 256; ++k) acc += row[k] * W[tid * 256 + k];
        logits[tid] = acc;
    }
    __syncthreads();
    if (tid == 0) {
        float m = -1e30f;
        for (int a = 0; a < 10; ++a) m = fmaxf(m, logits[a]);
        float s = 0.f;
        for (int a = 0; a < 10; ++a) s += expf(logits[a] - m);
        red[0] = m;
        red[1] = logf(s);
    }
    __syncthreads();
    if (tid < 10) out[g * 10 + tid] = logits[tid] - red[0] - red[1];
}

// ---------------------------------------------------------------------------

template <int C>
static void run_conv(float* X, float* M, float* AGG, float* WIT, float* WHT,
                     const float* W, const float* wih, const float* whh,
                     const float* bih, const float* bhh,
                     const int* rowstart, const int* csr_src,
                     int N, int E, hipStream_t stream) {
    int wt_threads = 3 * C * C;
    int wt_blocks = (wt_threads + 255) / 256;
    transpose_w_kernel<<<wt_blocks, 256, 0, stream>>>(wih, WIT, 3 * C, C);
    transpose_w_kernel<<<wt_blocks, 256, 0, stream>>>(whh, WHT, 3 * C, C);
    constexpr int BN = 2048 / C;
    int blocks = (N + BN - 1) / BN;
    constexpr int GPB = 256 / (C / 4);
    int gblocks = (N + GPB - 1) / GPB;
    for (int it = 0; it < 4; ++it) {
        matmul_kernel<C><<<blocks, 256, 0, stream>>>(X, W + (size_t)it * C * C, M, N);
        gather_kernel<C><<<gblocks, 256, 0, stream>>>(M, rowstart, csr_src, AGG, N);
        gru_kernel<C><<<blocks, 256, 0, stream>>>(X, AGG, WIT, WHT, bih, bhh, N);
    }
}

extern "C" void kernel_launch(void* const* d_in, const int* in_sizes, int n_in,
                              void* d_out, int out_size, void* d_ws, size_t ws_size,
                              hipStream_t stream) {
    const float* x = (const float*)d_in[0];
    const int* ei = (const int*)d_in[1];
    const int* batch = (const int*)d_in[2];
    const float* fc1W = (const float*)d_in[3];
    const float* fc1b = (const float*)d_in[4];
    const float* fc2W = (const float*)d_in[5];
    const float* fc2b = (const float*)d_in[6];
    const float* c1W = (const float*)d_in[7];
    const float* c1wih = (const float*)d_in[8];
    const float* c1whh = (const float*)d_in[9];
    const float* c1bih = (const float*)d_in[10];
    const float* c1bhh = (const float*)d_in[11];
    const float* c2W = (const float*)d_in[12];
    const float* c2wih = (const float*)d_in[13];
    const float* c2whh = (const float*)d_in[14];
    const float* c2bih = (const float*)d_in[15];
    const float* c2bhh = (const float*)d_in[16];
    const float* c3W = (const float*)d_in[17];
    const float* c3wih = (const float*)d_in[18];
    const float* c3whh = (const float*)d_in[19];
    const float* c3bih = (const float*)d_in[20];
    const float* c3bhh = (const float*)d_in[21];
    const float* bn1g = (const float*)d_in[22];
    const float* bn1b = (const float*)d_in[23];
    const float* bn1m = (const float*)d_in[24];
    const float* bn1v = (const float*)d_in[25];
    const float* bn2g = (const float*)d_in[26];
    const float* bn2b = (const float*)d_in[27];
    const float* bn2m = (const float*)d_in[28];
    const float* bn2v = (const float*)d_in[29];

    int N = in_sizes[0] / 32;
    int E = in_sizes[1] / 2;

    const size_t NODE_BUF = (size_t)N * 128;
    float* B0 = (float*)d_ws;
    float* B1 = B0 + NODE_BUF;
    float* B2 = B1 + NODE_BUF;
    float* WIT = B2 + NODE_BUF;
    float* WHT = WIT + 49152;
    float* G = WHT + 49152;
    float* G2 = G + 32768;
    int* deg = (int*)(G2 + 65536);
    int* scanout = deg + N;
    int* rowstart = scanout + N;     // N+1
    int* writeptr = rowstart + N + 1;
    int* blockSums = writeptr + N;   // 64
    int* csr_src = blockSums + 64;   // E

    // ---- build CSR by dst (once; reused by all 12 gathers) ----
    hipMemsetAsync(deg, 0, (size_t)N * sizeof(int), stream);
    int eblocks = (E + 255) / 256;
    hist_kernel<<<eblocks, 256, 0, stream>>>(ei, deg, E);
    int nscan = (N + 1023) / 1024;
    scan1_kernel<<<nscan, 256, 0, stream>>>(deg, scanout, blockSums, N);
    scan2_kernel<<<1, 64, 0, stream>>>(blockSums, nscan);
    scan3_kernel<<<(N + 255) / 256, 256, 0, stream>>>(scanout, blockSums, rowstart, writeptr, N, E);
    fill_kernel<<<eblocks, 256, 0, stream>>>(ei, writeptr, csr_src, E);

    // x -> B0 (conv1 state, [N,32])
    hipMemcpyAsync(B0, x, (size_t)N * 32 * sizeof(float),
                   hipMemcpyDeviceToDevice, stream);

    // conv1 (C=32)
    run_conv<32>(B0, B1, B2, WIT, WHT, c1W, c1wih, c1whh, c1bih, c1bhh,
                 rowstart, csr_src, N, E, stream);
    {
        long total = (long)N * 64;
        int blocks = (int)((total + 255) / 256);
        elu_bn_pad_kernel<32, 64><<<blocks, 256, 0, stream>>>(B0, B1, bn1g, bn1b, bn1m, bn1v, N);
    }

    // conv2 (C=64)
    run_conv<64>(B1, B0, B2, WIT, WHT, c2W, c2wih, c2whh, c2bih, c2bhh,
                 rowstart, csr_src, N, E, stream);
    {
        long total = (long)N * 128;
        int blocks = (int)((total + 255) / 256);
        elu_bn_pad_kernel<64, 128><<<blocks, 256, 0, stream>>>(B1, B0, bn2g, bn2b, bn2m, bn2v, N);
    }

    // conv3 (C=128)
    run_conv<128>(B0, B1, B2, WIT, WHT, c3W, c3wih, c3whh, c3bih, c3bhh,
                 rowstart, csr_src, N, E, stream);

    // pool
    hipMemsetAsync(G, 0, 256 * 128 * sizeof(float), stream);
    {
        long total = (long)N * 128;
        int blocks = (int)((total + 255) / 256);
        pool_elu_kernel<<<blocks, 256, 0, stream>>>(B0, batch, G, N);
    }

    fc1_kernel<<<256, 256, 0, stream>>>(G, fc1W, fc1b, G2);
    fc2_logsoftmax_kernel<<<256, 64, 0, stream>>>(G2, fc2W, fc2b, (float*)d_out);
}

// Round 4
// 1462.256 us; speedup vs baseline: 2.6000x; 1.4131x over previous
//
#include <hip/hip_runtime.h>
#include <math.h>

// ---------------------------------------------------------------------------
// GNN: 3x GatedGraphConv (C=32,64,128; 4 inner layers each) + BN + pool + MLP
// Round 4: split-bf16 MFMA (hi/lo) for near-fp32 accuracy at MFMA speed.
//   A*B ~= Ahi*Bhi + Ahi*Blo + Alo*Bhi  (3 mfma passes, lo*lo dropped)
// State X, M, AGG all fp32 (gather sums fp32, CSR-deterministic).
// ---------------------------------------------------------------------------

#define EPS_BN 1e-5f

typedef short short8 __attribute__((ext_vector_type(8)));
typedef float f32x4 __attribute__((ext_vector_type(4)));

__device__ __forceinline__ float elu_f(float v) {
    return v > 0.f ? v : expm1f(v);
}
__device__ __forceinline__ float sigmoid_f(float v) {
    return 1.f / (1.f + __expf(-v));
}
__device__ __forceinline__ float tanh_f(float v) {
    float e = __expf(2.f * v);
    return 1.f - 2.f / (e + 1.f);
}
__device__ __forceinline__ unsigned short f2bf(float f) {
    unsigned u = __float_as_uint(f);
    unsigned r = (u + 0x7FFF + ((u >> 16) & 1)) >> 16;
    return (unsigned short)r;
}
__device__ __forceinline__ float bf2f(unsigned short b) {
    return __uint_as_float(((unsigned)b) << 16);
}

// split 8 consecutive floats into hi/lo bf16 fragments
__device__ __forceinline__ void split8(const float* __restrict__ src,
                                       short8& hi, short8& lo) {
    float xv[8];
    *(float4*)&xv[0] = ((const float4*)src)[0];
    *(float4*)&xv[4] = ((const float4*)src)[1];
#pragma unroll
    for (int j = 0; j < 8; ++j) {
        unsigned short h = f2bf(xv[j]);
        hi[j] = (short)h;
        lo[j] = (short)f2bf(xv[j] - bf2f(h));
    }
}

// ------------------------- CSR construction -------------------------------

__global__ __launch_bounds__(256) void hist_kernel(
    const int* __restrict__ ei, int* __restrict__ deg, int E) {
    int e = blockIdx.x * 256 + threadIdx.x;
    if (e < E) atomicAdd(&deg[ei[E + e]], 1);
}

__global__ __launch_bounds__(256) void scan1_kernel(
    const int* __restrict__ deg, int* __restrict__ out,
    int* __restrict__ blockSums, int N) {
    __shared__ int sdata[256];
    int b = blockIdx.x, t = threadIdx.x;
    int base = b * 1024 + t * 4;
    int v[4], s = 0;
#pragma unroll
    for (int i = 0; i < 4; ++i) {
        v[i] = (base + i < N) ? deg[base + i] : 0;
        s += v[i];
    }
    sdata[t] = s;
    __syncthreads();
    for (int off = 1; off < 256; off <<= 1) {
        int x = (t >= off) ? sdata[t - off] : 0;
        __syncthreads();
        sdata[t] += x;
        __syncthreads();
    }
    int run = sdata[t] - s;
#pragma unroll
    for (int i = 0; i < 4; ++i) {
        if (base + i < N) out[base + i] = run;
        run += v[i];
    }
    if (t == 255) blockSums[b] = sdata[255];
}

__global__ void scan2_kernel(int* blockSums, int nb) {
    if (threadIdx.x == 0 && blockIdx.x == 0) {
        int run = 0;
        for (int i = 0; i < nb; ++i) {
            int v = blockSums[i];
            blockSums[i] = run;
            run += v;
        }
    }
}

__global__ __launch_bounds__(256) void scan3_kernel(
    const int* __restrict__ out, const int* __restrict__ blockSums,
    int* __restrict__ rowstart, int* __restrict__ writeptr, int N, int E) {
    int i = blockIdx.x * 256 + threadIdx.x;
    if (i < N) {
        int v = out[i] + blockSums[i >> 10];
        rowstart[i] = v;
        writeptr[i] = v;
    }
    if (i == 0) rowstart[N] = E;
}

__global__ __launch_bounds__(256) void fill_kernel(
    const int* __restrict__ ei, int* __restrict__ writeptr,
    int* __restrict__ csr_src, int E) {
    int e = blockIdx.x * 256 + threadIdx.x;
    if (e < E) {
        int d = ei[E + e];
        int p = atomicAdd(&writeptr[d], 1);
        csr_src[p] = ei[e];
    }
}

// ------------------------- weight swizzles (hi/lo) ------------------------
// mfma_f32_16x16x32_bf16 layouts:
//   A[m][k]: m = lane&15, k = (lane>>4)*8 + j
//   B[k][n]: n = lane&15, k = (lane>>4)*8 + j
//   C/D:     col = lane&15, row = (lane>>4)*4 + reg

// W: [4, C, C]; B[k][col] = W[l][k][col]
// slot = ks*NT + t ; element ((l*KS*NT + slot)*64 + lane)*8 + j
template <int C>
__global__ __launch_bounds__(256) void swizzle_w_kernel(
    const float* __restrict__ W, unsigned short* __restrict__ WsHi,
    unsigned short* __restrict__ WsLo) {
    constexpr int NT = C / 16;
    int idx = blockIdx.x * 256 + threadIdx.x;
    if (idx >= 4 * C * C) return;
    int per = C * C;
    int l = idx / per;
    int r0 = idx % per;
    int j = r0 & 7;
    int lane = (r0 >> 3) & 63;
    int rest = r0 >> 9;
    int t = rest % NT;
    int ks = rest / NT;
    int k = ks * 32 + (lane >> 4) * 8 + j;
    int col = t * 16 + (lane & 15);
    float v = W[(size_t)l * per + k * C + col];
    unsigned short h = f2bf(v);
    WsHi[idx] = h;
    WsLo[idx] = f2bf(v - bf2f(h));
}

// GRU concat-B: K = 2C (k<C: wih on AGG; k>=C: whh on X).
// tslot groups per ks: [0,CT): r ; [CT,2CT): z ; [2CT,3CT): k<C ? in : hn
template <int C>
__global__ __launch_bounds__(256) void swizzle_b2_kernel(
    const float* __restrict__ wih, const float* __restrict__ whh,
    unsigned short* __restrict__ BsHi, unsigned short* __restrict__ BsLo) {
    constexpr int CT = C / 16;
    int idx = blockIdx.x * 256 + threadIdx.x;
    if (idx >= 6 * C * C) return;
    int j = idx & 7;
    int lane = (idx >> 3) & 63;
    int rest = idx >> 9;
    int tslot = rest % (3 * CT);
    int ks = rest / (3 * CT);
    int k = ks * 32 + (lane >> 4) * 8 + j;
    int g = tslot / CT;
    int lt = tslot % CT;
    int c = lt * 16 + (lane & 15);
    int row = g * C + c;
    float v = (k < C) ? wih[(size_t)row * C + k] : whh[(size_t)row * C + (k - C)];
    unsigned short h = f2bf(v);
    BsHi[idx] = h;
    BsLo[idx] = f2bf(v - bf2f(h));
}

// ------------------------- M = X @ W (split-bf16 MFMA) --------------------

template <int C>
__global__ __launch_bounds__(256, 4) void matmul_mfma_kernel(
    const float* __restrict__ X, const unsigned short* __restrict__ WsHi,
    const unsigned short* __restrict__ WsLo, float* __restrict__ M, int N) {
    constexpr int NT = C / 16;
    constexpr int KS = C / 32;
    int wave = threadIdx.x >> 6;
    int lane = threadIdx.x & 63;
    int quad = lane >> 4;
    int l16 = lane & 15;
    int node0 = blockIdx.x * 64 + wave * 16;
    int arow = node0 + l16;
    if (arow >= N) arow = N - 1;  // dup rows only affect guarded output rows
    f32x4 acc[NT];
#pragma unroll
    for (int t = 0; t < NT; ++t) acc[t] = (f32x4){0.f, 0.f, 0.f, 0.f};
    const short8* bhi = (const short8*)WsHi;
    const short8* blo = (const short8*)WsLo;
    for (int ks = 0; ks < KS; ++ks) {
        short8 ahi, alo;
        split8(X + (size_t)arow * C + ks * 32 + quad * 8, ahi, alo);
        const short8* bh = bhi + (size_t)(ks * NT) * 64 + lane;
        const short8* bl = blo + (size_t)(ks * NT) * 64 + lane;
#pragma unroll
        for (int t = 0; t < NT; ++t) {
            acc[t] = __builtin_amdgcn_mfma_f32_16x16x32_bf16(ahi, bh[t * 64], acc[t], 0, 0, 0);
            acc[t] = __builtin_amdgcn_mfma_f32_16x16x32_bf16(alo, bh[t * 64], acc[t], 0, 0, 0);
            acc[t] = __builtin_amdgcn_mfma_f32_16x16x32_bf16(ahi, bl[t * 64], acc[t], 0, 0, 0);
        }
    }
#pragma unroll
    for (int t = 0; t < NT; ++t) {
        int c = t * 16 + l16;
#pragma unroll
        for (int r = 0; r < 4; ++r) {
            int node = node0 + quad * 4 + r;
            if (node < N) M[(size_t)node * C + c] = acc[t][r];
        }
    }
}

// ------------------------- gather (fp32) ----------------------------------

template <int C>
__global__ __launch_bounds__(256) void gather_kernel(
    const float* __restrict__ M, const int* __restrict__ rowstart,
    const int* __restrict__ csr_src, float* __restrict__ AGG, int N) {
    constexpr int LPG = C / 4;
    constexpr int GPB = 256 / LPG;
    int lane = threadIdx.x % LPG;
    int grp = threadIdx.x / LPG;
    int d = blockIdx.x * GPB + grp;
    if (d >= N) return;
    int p = rowstart[d];
    int p1 = rowstart[d + 1];
    float4 acc = {0.f, 0.f, 0.f, 0.f};
    for (; p < p1; ++p) {
        int s = csr_src[p];
        float4 v = ((const float4*)&M[(size_t)s * C])[lane];
        acc.x += v.x;
        acc.y += v.y;
        acc.z += v.z;
        acc.w += v.w;
    }
    ((float4*)&AGG[(size_t)d * C])[lane] = acc;
}

// ------------------------- GRU cell (split-bf16 MFMA) ---------------------

template <int C>
__global__ __launch_bounds__(256, 2) void gru_mfma_kernel(
    float* __restrict__ X, const float* __restrict__ AGG,
    const unsigned short* __restrict__ BsHi,
    const unsigned short* __restrict__ BsLo,
    const float* __restrict__ bi, const float* __restrict__ bh, int N) {
    constexpr int CT = C / 16;
    constexpr int KS = 2 * C / 32;
    int wave = threadIdx.x >> 6;
    int lane = threadIdx.x & 63;
    int quad = lane >> 4;
    int l16 = lane & 15;
    int node0 = blockIdx.x * 64 + wave * 16;
    int arow = node0 + l16;
    if (arow >= N) arow = N - 1;
    const float* aggRow = AGG + (size_t)arow * C;
    const float* xRow = X + (size_t)arow * C;
    f32x4 accR[CT], accZ[CT], accN[CT], accH[CT];
#pragma unroll
    for (int t = 0; t < CT; ++t) {
        accR[t] = (f32x4){0.f, 0.f, 0.f, 0.f};
        accZ[t] = (f32x4){0.f, 0.f, 0.f, 0.f};
        accN[t] = (f32x4){0.f, 0.f, 0.f, 0.f};
        accH[t] = (f32x4){0.f, 0.f, 0.f, 0.f};
    }
    const short8* bhi = (const short8*)BsHi;
    const short8* blo = (const short8*)BsLo;
    for (int ks = 0; ks < KS; ++ks) {
        int k0 = ks * 32 + quad * 8;
        short8 ahi, alo;
        if (k0 < C)
            split8(aggRow + k0, ahi, alo);
        else
            split8(xRow + (k0 - C), ahi, alo);
        const short8* bh2 = bhi + (size_t)(ks * 3 * CT) * 64 + lane;
        const short8* bl2 = blo + (size_t)(ks * 3 * CT) * 64 + lane;
#pragma unroll
        for (int t = 0; t < CT; ++t) {
            accR[t] = __builtin_amdgcn_mfma_f32_16x16x32_bf16(ahi, bh2[t * 64], accR[t], 0, 0, 0);
            accR[t] = __builtin_amdgcn_mfma_f32_16x16x32_bf16(alo, bh2[t * 64], accR[t], 0, 0, 0);
            accR[t] = __builtin_amdgcn_mfma_f32_16x16x32_bf16(ahi, bl2[t * 64], accR[t], 0, 0, 0);
        }
#pragma unroll
        for (int t = 0; t < CT; ++t) {
            accZ[t] = __builtin_amdgcn_mfma_f32_16x16x32_bf16(ahi, bh2[(CT + t) * 64], accZ[t], 0, 0, 0);
            accZ[t] = __builtin_amdgcn_mfma_f32_16x16x32_bf16(alo, bh2[(CT + t) * 64], accZ[t], 0, 0, 0);
            accZ[t] = __builtin_amdgcn_mfma_f32_16x16x32_bf16(ahi, bl2[(CT + t) * 64], accZ[t], 0, 0, 0);
        }
        if (ks < KS / 2) {
#pragma unroll
            for (int t = 0; t < CT; ++t) {
                accN[t] = __builtin_amdgcn_mfma_f32_16x16x32_bf16(ahi, bh2[(2 * CT + t) * 64], accN[t], 0, 0, 0);
                accN[t] = __builtin_amdgcn_mfma_f32_16x16x32_bf16(alo, bh2[(2 * CT + t) * 64], accN[t], 0, 0, 0);
                accN[t] = __builtin_amdgcn_mfma_f32_16x16x32_bf16(ahi, bl2[(2 * CT + t) * 64], accN[t], 0, 0, 0);
            }
        } else {
#pragma unroll
            for (int t = 0; t < CT; ++t) {
                accH[t] = __builtin_amdgcn_mfma_f32_16x16x32_bf16(ahi, bh2[(2 * CT + t) * 64], accH[t], 0, 0, 0);
                accH[t] = __builtin_amdgcn_mfma_f32_16x16x32_bf16(alo, bh2[(2 * CT + t) * 64], accH[t], 0, 0, 0);
                accH[t] = __builtin_amdgcn_mfma_f32_16x16x32_bf16(ahi, bl2[(2 * CT + t) * 64], accH[t], 0, 0, 0);
            }
        }
    }
#pragma unroll
    for (int t = 0; t < CT; ++t) {
        int c = t * 16 + l16;
        float bir = bi[c], biz = bi[C + c], bin = bi[2 * C + c];
        float bhr = bh[c], bhz = bh[C + c], bhn = bh[2 * C + c];
#pragma unroll
        for (int r = 0; r < 4; ++r) {
            int node = node0 + quad * 4 + r;
            if (node < N) {
                float rv = sigmoid_f(accR[t][r] + bir + bhr);
                float zv = sigmoid_f(accZ[t][r] + biz + bhz);
                float nv = tanh_f(accN[t][r] + bin + rv * (accH[t][r] + bhn));
                size_t gi = (size_t)node * C + c;
                float xo = X[gi];
                X[gi] = (1.f - zv) * nv + zv * xo;
            }
        }
    }
}

// ------------------------- epilogues --------------------------------------

template <int Cin, int Cout>
__global__ __launch_bounds__(256) void elu_bn_pad_kernel(
    const float* __restrict__ Xin, float* __restrict__ Xout,
    const float* __restrict__ gamma, const float* __restrict__ beta,
    const float* __restrict__ mean, const float* __restrict__ var, int N) {
    long t = (long)blockIdx.x * 256 + threadIdx.x;
    long total = (long)N * Cout;
    if (t >= total) return;
    int n = (int)(t / Cout);
    int c = (int)(t & (Cout - 1));
    float v = 0.f;
    if (c < Cin) {
        float x = Xin[(size_t)n * Cin + c];
        x = elu_f(x);
        v = (x - mean[c]) * rsqrtf(var[c] + EPS_BN) * gamma[c] + beta[c];
    }
    Xout[t] = v;
}

__global__ __launch_bounds__(256) void pool_elu_kernel(
    const float* __restrict__ X, const int* __restrict__ batch,
    float* __restrict__ G, int N) {
    long t = (long)blockIdx.x * 256 + threadIdx.x;
    if (t >= (long)N * 128) return;
    int n = (int)(t >> 7);
    int c = (int)(t & 127);
    float v = elu_f(X[t]);
    atomicAdd(&G[batch[n] * 128 + c], v);
}

__global__ __launch_bounds__(256) void fc1_kernel(
    const float* __restrict__ G, const float* __restrict__ W,
    const float* __restrict__ b, float* __restrict__ G2) {
    __shared__ float row[128];
    int g = blockIdx.x;
    int j = threadIdx.x;
    if (j < 128) row[j] = G[g * 128 + j];
    __syncthreads();
    float acc = b[j];
    for (int k = 0; k < 128; ++k) acc += row[k] * W[j * 128 + k];
    G2[g * 256 + j] = elu_f(acc);
}

__global__ __launch_bounds__(64) void fc2_logsoftmax_kernel(
    const float* __restrict__ G2, const float* __restrict__ W,
    const float* __restrict__ b, float* __restrict__ out) {
    __shared__ float row[256];
    __shared__ float logits[10];
    __shared__ float red[2];
    int g = blockIdx.x;
    int tid = threadIdx.x;
    for (int i = tid; i < 256; i += 64) row[i] = G2[g * 256 + i];
    __syncthreads();
    if (tid < 10) {
        float acc = b[tid];
        for (int k = 0; k < 256; ++k) acc += row[k] * W[tid * 256 + k];
        logits[tid] = acc;
    }
    __syncthreads();
    if (tid == 0) {
        float m = -1e30f;
        for (int a = 0; a < 10; ++a) m = fmaxf(m, logits[a]);
        float s = 0.f;
        for (int a = 0; a < 10; ++a) s += expf(logits[a] - m);
        red[0] = m;
        red[1] = logf(s);
    }
    __syncthreads();
    if (tid < 10) out[g * 10 + tid] = logits[tid] - red[0] - red[1];
}

// ---------------------------------------------------------------------------

template <int C>
static void run_conv(float* X, float* M, float* AGG,
                     unsigned short* WsHi, unsigned short* WsLo,
                     unsigned short* BsHi, unsigned short* BsLo,
                     const float* W, const float* wih, const float* whh,
                     const float* bih, const float* bhh,
                     const int* rowstart, const int* csr_src,
                     int N, int E, hipStream_t stream) {
    swizzle_w_kernel<C><<<(4 * C * C + 255) / 256, 256, 0, stream>>>(W, WsHi, WsLo);
    swizzle_b2_kernel<C><<<(6 * C * C + 255) / 256, 256, 0, stream>>>(wih, whh, BsHi, BsLo);
    int blocks = (N + 63) / 64;
    constexpr int GPB = 256 / (C / 4);
    int gblocks = (N + GPB - 1) / GPB;
    for (int it = 0; it < 4; ++it) {
        matmul_mfma_kernel<C><<<blocks, 256, 0, stream>>>(
            X, WsHi + (size_t)it * C * C, WsLo + (size_t)it * C * C, M, N);
        gather_kernel<C><<<gblocks, 256, 0, stream>>>(M, rowstart, csr_src, AGG, N);
        gru_mfma_kernel<C><<<blocks, 256, 0, stream>>>(X, AGG, BsHi, BsLo, bih, bhh, N);
    }
}

extern "C" void kernel_launch(void* const* d_in, const int* in_sizes, int n_in,
                              void* d_out, int out_size, void* d_ws, size_t ws_size,
                              hipStream_t stream) {
    const float* x = (const float*)d_in[0];
    const int* ei = (const int*)d_in[1];
    const int* batch = (const int*)d_in[2];
    const float* fc1W = (const float*)d_in[3];
    const float* fc1b = (const float*)d_in[4];
    const float* fc2W = (const float*)d_in[5];
    const float* fc2b = (const float*)d_in[6];
    const float* c1W = (const float*)d_in[7];
    const float* c1wih = (const float*)d_in[8];
    const float* c1whh = (const float*)d_in[9];
    const float* c1bih = (const float*)d_in[10];
    const float* c1bhh = (const float*)d_in[11];
    const float* c2W = (const float*)d_in[12];
    const float* c2wih = (const float*)d_in[13];
    const float* c2whh = (const float*)d_in[14];
    const float* c2bih = (const float*)d_in[15];
    const float* c2bhh = (const float*)d_in[16];
    const float* c3W = (const float*)d_in[17];
    const float* c3wih = (const float*)d_in[18];
    const float* c3whh = (const float*)d_in[19];
    const float* c3bih = (const float*)d_in[20];
    const float* c3bhh = (const float*)d_in[21];
    const float* bn1g = (const float*)d_in[22];
    const float* bn1b = (const float*)d_in[23];
    const float* bn1m = (const float*)d_in[24];
    const float* bn1v = (const float*)d_in[25];
    const float* bn2g = (const float*)d_in[26];
    const float* bn2b = (const float*)d_in[27];
    const float* bn2m = (const float*)d_in[28];
    const float* bn2v = (const float*)d_in[29];

    int N = in_sizes[0] / 32;
    int E = in_sizes[1] / 2;

    const size_t NODE_BUF = (size_t)N * 128;
    float* B0 = (float*)d_ws;
    float* B1 = B0 + NODE_BUF;
    float* B2 = B1 + NODE_BUF;
    unsigned short* WsHi = (unsigned short*)(B2 + NODE_BUF);  // 4*C*C <= 65536
    unsigned short* WsLo = WsHi + 65536;
    unsigned short* BsHi = WsLo + 65536;                      // 6*C*C <= 98304
    unsigned short* BsLo = BsHi + 98304;
    float* G = (float*)(BsLo + 98304);
    float* G2 = G + 32768;
    int* deg = (int*)(G2 + 65536);
    int* scanout = deg + N;
    int* rowstart = scanout + N;
    int* writeptr = rowstart + N + 1;
    int* blockSums = writeptr + N;
    int* csr_src = blockSums + 64;

    // ---- build CSR by dst (once; reused by all 12 gathers) ----
    hipMemsetAsync(deg, 0, (size_t)N * sizeof(int), stream);
    int eblocks = (E + 255) / 256;
    hist_kernel<<<eblocks, 256, 0, stream>>>(ei, deg, E);
    int nscan = (N + 1023) / 1024;
    scan1_kernel<<<nscan, 256, 0, stream>>>(deg, scanout, blockSums, N);
    scan2_kernel<<<1, 64, 0, stream>>>(blockSums, nscan);
    scan3_kernel<<<(N + 255) / 256, 256, 0, stream>>>(scanout, blockSums, rowstart, writeptr, N, E);
    fill_kernel<<<eblocks, 256, 0, stream>>>(ei, writeptr, csr_src, E);

    // x -> B0 (conv1 state, [N,32])
    hipMemcpyAsync(B0, x, (size_t)N * 32 * sizeof(float),
                   hipMemcpyDeviceToDevice, stream);

    // conv1 (C=32): X=B0, M=B1, AGG=B2
    run_conv<32>(B0, B1, B2, WsHi, WsLo, BsHi, BsLo,
                 c1W, c1wih, c1whh, c1bih, c1bhh, rowstart, csr_src, N, E, stream);
    elu_bn_pad_kernel<32, 64><<<(int)(((long)N * 64 + 255) / 256), 256, 0, stream>>>(
        B0, B1, bn1g, bn1b, bn1m, bn1v, N);

    // conv2 (C=64): X=B1, M=B0, AGG=B2
    run_conv<64>(B1, B0, B2, WsHi, WsLo, BsHi, BsLo,
                 c2W, c2wih, c2whh, c2bih, c2bhh, rowstart, csr_src, N, E, stream);
    elu_bn_pad_kernel<64, 128><<<(int)(((long)N * 128 + 255) / 256), 256, 0, stream>>>(
        B1, B0, bn2g, bn2b, bn2m, bn2v, N);

    // conv3 (C=128): X=B0, M=B1, AGG=B2
    run_conv<128>(B0, B1, B2, WsHi, WsLo, BsHi, BsLo,
                  c3W, c3wih, c3whh, c3bih, c3bhh, rowstart, csr_src, N, E, stream);

    // pool
    hipMemsetAsync(G, 0, 256 * 128 * sizeof(float), stream);
    pool_elu_kernel<<<(int)(((long)N * 128 + 255) / 256), 256, 0, stream>>>(B0, batch, G, N);

    fc1_kernel<<<256, 256, 0, stream>>>(G, fc1W, fc1b, G2);
    fc2_logsoftmax_kernel<<<256, 64, 0, stream>>>(G2, fc2W, fc2b, (float*)d_out);
}

// Round 5
// 1429.317 us; speedup vs baseline: 2.6599x; 1.0230x over previous
//
#include <hip/hip_runtime.h>
#include <math.h>

// ---------------------------------------------------------------------------
// GNN: 3x GatedGraphConv (C=32,64,128; 4 inner layers each) + BN + pool + MLP
// Round 5: split-bf16 (hi/lo plane) storage for ALL GEMM operands, 4-A-tile
// column-split MFMA blocks (4x B reuse), no in-loop split VALU work.
//   A*B ~= Ahi*Bhi + Alo*Bhi + Ahi*Blo   (lo*lo dropped, ~1e-5 rel error)
// ---------------------------------------------------------------------------

#define EPS_BN 1e-5f

typedef short short8 __attribute__((ext_vector_type(8)));
typedef float f32x4 __attribute__((ext_vector_type(4)));

__device__ __forceinline__ float elu_f(float v) {
    return v > 0.f ? v : expm1f(v);
}
__device__ __forceinline__ float sigmoid_f(float v) {
    return 1.f / (1.f + __expf(-v));
}
__device__ __forceinline__ float tanh_f(float v) {
    float e = __expf(2.f * v);
    return 1.f - 2.f / (e + 1.f);
}
__device__ __forceinline__ unsigned short f2bf(float f) {
    unsigned u = __float_as_uint(f);
    unsigned r = (u + 0x7FFF + ((u >> 16) & 1)) >> 16;
    return (unsigned short)r;
}
__device__ __forceinline__ float bf2f(unsigned short b) {
    return __uint_as_float(((unsigned)b) << 16);
}
// write v as hi/lo bf16 pair
__device__ __forceinline__ void put_hl(unsigned short* __restrict__ hi,
                                       unsigned short* __restrict__ lo,
                                       size_t idx, float v) {
    unsigned short h = f2bf(v);
    hi[idx] = h;
    lo[idx] = f2bf(v - bf2f(h));
}

// ------------------------- CSR construction -------------------------------

__global__ __launch_bounds__(256) void hist_kernel(
    const int* __restrict__ ei, int* __restrict__ deg, int E) {
    int e = blockIdx.x * 256 + threadIdx.x;
    if (e < E) atomicAdd(&deg[ei[E + e]], 1);
}

__global__ __launch_bounds__(256) void scan1_kernel(
    const int* __restrict__ deg, int* __restrict__ out,
    int* __restrict__ blockSums, int N) {
    __shared__ int sdata[256];
    int b = blockIdx.x, t = threadIdx.x;
    int base = b * 1024 + t * 4;
    int v[4], s = 0;
#pragma unroll
    for (int i = 0; i < 4; ++i) {
        v[i] = (base + i < N) ? deg[base + i] : 0;
        s += v[i];
    }
    sdata[t] = s;
    __syncthreads();
    for (int off = 1; off < 256; off <<= 1) {
        int x = (t >= off) ? sdata[t - off] : 0;
        __syncthreads();
        sdata[t] += x;
        __syncthreads();
    }
    int run = sdata[t] - s;
#pragma unroll
    for (int i = 0; i < 4; ++i) {
        if (base + i < N) out[base + i] = run;
        run += v[i];
    }
    if (t == 255) blockSums[b] = sdata[255];
}

__global__ void scan2_kernel(int* blockSums, int nb) {
    if (threadIdx.x == 0 && blockIdx.x == 0) {
        int run = 0;
        for (int i = 0; i < nb; ++i) {
            int v = blockSums[i];
            blockSums[i] = run;
            run += v;
        }
    }
}

__global__ __launch_bounds__(256) void scan3_kernel(
    const int* __restrict__ out, const int* __restrict__ blockSums,
    int* __restrict__ rowstart, int* __restrict__ writeptr, int N, int E) {
    int i = blockIdx.x * 256 + threadIdx.x;
    if (i < N) {
        int v = out[i] + blockSums[i >> 10];
        rowstart[i] = v;
        writeptr[i] = v;
    }
    if (i == 0) rowstart[N] = E;
}

__global__ __launch_bounds__(256) void fill_kernel(
    const int* __restrict__ ei, int* __restrict__ writeptr,
    int* __restrict__ csr_src, int E) {
    int e = blockIdx.x * 256 + threadIdx.x;
    if (e < E) {
        int d = ei[E + e];
        int p = atomicAdd(&writeptr[d], 1);
        csr_src[p] = ei[e];
    }
}

// ------------------------- weight swizzles (hi/lo) ------------------------
// mfma_f32_16x16x32_bf16 layouts:
//   A[m][k]: m = lane&15, k = (lane>>4)*8 + j
//   B[k][n]: n = lane&15, k = (lane>>4)*8 + j
//   C/D:     col = lane&15, row = (lane>>4)*4 + reg

// W: [4, C, C]; slot = ks*NT + t (t = column tile); elem (slot*64+lane)*8+j
template <int C>
__global__ __launch_bounds__(256) void swizzle_w_kernel(
    const float* __restrict__ W, unsigned short* __restrict__ WsHi,
    unsigned short* __restrict__ WsLo) {
    constexpr int NT = C / 16;
    int idx = blockIdx.x * 256 + threadIdx.x;
    if (idx >= 4 * C * C) return;
    int per = C * C;
    int l = idx / per;
    int r0 = idx % per;
    int j = r0 & 7;
    int lane = (r0 >> 3) & 63;
    int rest = r0 >> 9;
    int t = rest % NT;
    int ks = rest / NT;
    int k = ks * 32 + (lane >> 4) * 8 + j;
    int col = t * 16 + (lane & 15);
    float v = W[(size_t)l * per + k * C + col];
    unsigned short h = f2bf(v);
    WsHi[idx] = h;
    WsLo[idx] = f2bf(v - bf2f(h));
}

// GRU concat-B: K = 2C (k<C: wih on AGG; k>=C: whh on X).
// tslot per ks: [0,CT): r ; [CT,2CT): z ; [2CT,3CT): k<C ? in : hn
template <int C>
__global__ __launch_bounds__(256) void swizzle_b2_kernel(
    const float* __restrict__ wih, const float* __restrict__ whh,
    unsigned short* __restrict__ BsHi, unsigned short* __restrict__ BsLo) {
    constexpr int CT = C / 16;
    int idx = blockIdx.x * 256 + threadIdx.x;
    if (idx >= 6 * C * C) return;
    int j = idx & 7;
    int lane = (idx >> 3) & 63;
    int rest = idx >> 9;
    int tslot = rest % (3 * CT);
    int ks = rest / (3 * CT);
    int k = ks * 32 + (lane >> 4) * 8 + j;
    int g = tslot / CT;
    int lt = tslot % CT;
    int c = lt * 16 + (lane & 15);
    int row = g * C + c;
    float v = (k < C) ? wih[(size_t)row * C + k] : whh[(size_t)row * C + (k - C)];
    unsigned short h = f2bf(v);
    BsHi[idx] = h;
    BsLo[idx] = f2bf(v - bf2f(h));
}

// ------------------------- matmul: M = H @ W ------------------------------
// 4-A-tile column-split version (C = 64 or 128). Block = 4 waves = 64 nodes;
// wave w computes column tiles [w*CTW, (w+1)*CTW).

template <int C>
__global__ __launch_bounds__(256, 4) void matmul_mfma4_kernel(
    const unsigned short* __restrict__ Hhi, const unsigned short* __restrict__ Hlo,
    const unsigned short* __restrict__ WsHi, const unsigned short* __restrict__ WsLo,
    unsigned short* __restrict__ Mhi, unsigned short* __restrict__ Mlo, int N) {
    constexpr int NT = C / 16;
    constexpr int KS = C / 32;
    constexpr int CTW = NT / 4;
    int wave = threadIdx.x >> 6;
    int lane = threadIdx.x & 63;
    int quad = lane >> 4;
    int l16 = lane & 15;
    int node0 = blockIdx.x * 64;
    int arow[4];
#pragma unroll
    for (int t = 0; t < 4; ++t) {
        int r = node0 + t * 16 + l16;
        arow[t] = r < N ? r : N - 1;
    }
    f32x4 acc[CTW][4];
#pragma unroll
    for (int ct = 0; ct < CTW; ++ct)
#pragma unroll
        for (int t = 0; t < 4; ++t) acc[ct][t] = (f32x4){0.f, 0.f, 0.f, 0.f};
    const short8* bhi = (const short8*)WsHi;
    const short8* blo = (const short8*)WsLo;
    for (int ks = 0; ks < KS; ++ks) {
        int k0 = ks * 32 + quad * 8;
        short8 ahi[4], alo[4];
#pragma unroll
        for (int t = 0; t < 4; ++t) {
            ahi[t] = *(const short8*)(Hhi + (size_t)arow[t] * C + k0);
            alo[t] = *(const short8*)(Hlo + (size_t)arow[t] * C + k0);
        }
#pragma unroll
        for (int ct = 0; ct < CTW; ++ct) {
            int tslot = ks * NT + wave * CTW + ct;
            short8 bhf = bhi[(size_t)tslot * 64 + lane];
            short8 blf = blo[(size_t)tslot * 64 + lane];
#pragma unroll
            for (int t = 0; t < 4; ++t) {
                acc[ct][t] = __builtin_amdgcn_mfma_f32_16x16x32_bf16(ahi[t], bhf, acc[ct][t], 0, 0, 0);
                acc[ct][t] = __builtin_amdgcn_mfma_f32_16x16x32_bf16(alo[t], bhf, acc[ct][t], 0, 0, 0);
                acc[ct][t] = __builtin_amdgcn_mfma_f32_16x16x32_bf16(ahi[t], blf, acc[ct][t], 0, 0, 0);
            }
        }
    }
#pragma unroll
    for (int ct = 0; ct < CTW; ++ct) {
        int c = (wave * CTW + ct) * 16 + l16;
#pragma unroll
        for (int t = 0; t < 4; ++t) {
#pragma unroll
            for (int r = 0; r < 4; ++r) {
                int node = node0 + t * 16 + quad * 4 + r;
                if (node < N) put_hl(Mhi, Mlo, (size_t)node * C + c, acc[ct][t][r]);
            }
        }
    }
}

// C=32 matmul: classic 1-A-tile per wave (B is tiny, L1-resident)
__global__ __launch_bounds__(256, 4) void matmul_mfma32_kernel(
    const unsigned short* __restrict__ Hhi, const unsigned short* __restrict__ Hlo,
    const unsigned short* __restrict__ WsHi, const unsigned short* __restrict__ WsLo,
    unsigned short* __restrict__ Mhi, unsigned short* __restrict__ Mlo, int N) {
    constexpr int C = 32;
    int wave = threadIdx.x >> 6;
    int lane = threadIdx.x & 63;
    int quad = lane >> 4;
    int l16 = lane & 15;
    int node0 = blockIdx.x * 64 + wave * 16;
    int ar = node0 + l16;
    if (ar >= N) ar = N - 1;
    int k0 = quad * 8;
    short8 ahi = *(const short8*)(Hhi + (size_t)ar * C + k0);
    short8 alo = *(const short8*)(Hlo + (size_t)ar * C + k0);
    const short8* bhi = (const short8*)WsHi;
    const short8* blo = (const short8*)WsLo;
    f32x4 acc[2];
#pragma unroll
    for (int t = 0; t < 2; ++t) {
        acc[t] = (f32x4){0.f, 0.f, 0.f, 0.f};
        short8 bhf = bhi[(size_t)t * 64 + lane];
        short8 blf = blo[(size_t)t * 64 + lane];
        acc[t] = __builtin_amdgcn_mfma_f32_16x16x32_bf16(ahi, bhf, acc[t], 0, 0, 0);
        acc[t] = __builtin_amdgcn_mfma_f32_16x16x32_bf16(alo, bhf, acc[t], 0, 0, 0);
        acc[t] = __builtin_amdgcn_mfma_f32_16x16x32_bf16(ahi, blf, acc[t], 0, 0, 0);
    }
#pragma unroll
    for (int t = 0; t < 2; ++t) {
        int c = t * 16 + l16;
#pragma unroll
        for (int r = 0; r < 4; ++r) {
            int node = node0 + quad * 4 + r;
            if (node < N) put_hl(Mhi, Mlo, (size_t)node * C + c, acc[t][r]);
        }
    }
}

// ------------------------- gather: AGG[d] = sum M[src] --------------------

template <int C>
__global__ __launch_bounds__(256) void gather_kernel(
    const unsigned short* __restrict__ Mhi, const unsigned short* __restrict__ Mlo,
    const int* __restrict__ rowstart, const int* __restrict__ csr_src,
    unsigned short* __restrict__ AGhi, unsigned short* __restrict__ AGlo, int N) {
    constexpr int LPG = C / 4;
    constexpr int GPB = 256 / LPG;
    int lane = threadIdx.x % LPG;
    int grp = threadIdx.x / LPG;
    int d = blockIdx.x * GPB + grp;
    if (d >= N) return;
    int p = rowstart[d];
    int p1 = rowstart[d + 1];
    float a0 = 0.f, a1 = 0.f, a2 = 0.f, a3 = 0.f;
    for (; p < p1; ++p) {
        int s = csr_src[p];
        ushort4 vh = ((const ushort4*)(Mhi + (size_t)s * C))[lane];
        ushort4 vl = ((const ushort4*)(Mlo + (size_t)s * C))[lane];
        a0 += bf2f(vh.x) + bf2f(vl.x);
        a1 += bf2f(vh.y) + bf2f(vl.y);
        a2 += bf2f(vh.z) + bf2f(vl.z);
        a3 += bf2f(vh.w) + bf2f(vl.w);
    }
    size_t base = (size_t)d * C + lane * 4;
    put_hl(AGhi, AGlo, base + 0, a0);
    put_hl(AGhi, AGlo, base + 1, a1);
    put_hl(AGhi, AGlo, base + 2, a2);
    put_hl(AGhi, AGlo, base + 3, a3);
}

// ------------------------- GRU cell ---------------------------------------
// 4-A-tile column-split (C = 64 or 128): block = 4 waves = 64 nodes; wave w
// owns column tiles [w*CTW, (w+1)*CTW) of every gate, so the gate combine is
// wave-local. Waves share A rows -> __syncthreads() before in-place epilogue.

template <int C>
__global__ __launch_bounds__(256, (C == 128 ? 2 : 3)) void gru_mfma4_kernel(
    unsigned short* __restrict__ Hhi, unsigned short* __restrict__ Hlo,
    const unsigned short* __restrict__ AGhi, const unsigned short* __restrict__ AGlo,
    const unsigned short* __restrict__ BsHi, const unsigned short* __restrict__ BsLo,
    const float* __restrict__ biasI, const float* __restrict__ biasH, int N) {
    constexpr int CT = C / 16;
    constexpr int KS = C / 16;  // 2C/32
    constexpr int CTW = C / 64;
    int wave = threadIdx.x >> 6;
    int lane = threadIdx.x & 63;
    int quad = lane >> 4;
    int l16 = lane & 15;
    int node0 = blockIdx.x * 64;
    int arow[4];
#pragma unroll
    for (int t = 0; t < 4; ++t) {
        int r = node0 + t * 16 + l16;
        arow[t] = r < N ? r : N - 1;
    }
    f32x4 accR[CTW][4], accZ[CTW][4], accN[CTW][4], accH[CTW][4];
#pragma unroll
    for (int ct = 0; ct < CTW; ++ct)
#pragma unroll
        for (int t = 0; t < 4; ++t) {
            accR[ct][t] = (f32x4){0.f, 0.f, 0.f, 0.f};
            accZ[ct][t] = (f32x4){0.f, 0.f, 0.f, 0.f};
            accN[ct][t] = (f32x4){0.f, 0.f, 0.f, 0.f};
            accH[ct][t] = (f32x4){0.f, 0.f, 0.f, 0.f};
        }
    const short8* bhi = (const short8*)BsHi;
    const short8* blo = (const short8*)BsLo;

#define GRU_KS_BODY(KS0, KS1, SRCHI, SRCLO, KOFF, ACC3)                         \
    for (int ks = (KS0); ks < (KS1); ++ks) {                                    \
        int k0 = ks * 32 + quad * 8 - (KOFF);                                   \
        short8 ahi[4], alo[4];                                                  \
        _Pragma("unroll") for (int t = 0; t < 4; ++t) {                         \
            ahi[t] = *(const short8*)((SRCHI) + (size_t)arow[t] * C + k0);      \
            alo[t] = *(const short8*)((SRCLO) + (size_t)arow[t] * C + k0);      \
        }                                                                       \
        _Pragma("unroll") for (int ct = 0; ct < CTW; ++ct) {                    \
            int ts0 = ks * 3 * CT + wave * CTW + ct;                            \
            short8 bhf = bhi[(size_t)ts0 * 64 + lane];                          \
            short8 blf = blo[(size_t)ts0 * 64 + lane];                          \
            _Pragma("unroll") for (int t = 0; t < 4; ++t) {                     \
                accR[ct][t] = __builtin_amdgcn_mfma_f32_16x16x32_bf16(ahi[t], bhf, accR[ct][t], 0, 0, 0); \
                accR[ct][t] = __builtin_amdgcn_mfma_f32_16x16x32_bf16(alo[t], bhf, accR[ct][t], 0, 0, 0); \
                accR[ct][t] = __builtin_amdgcn_mfma_f32_16x16x32_bf16(ahi[t], blf, accR[ct][t], 0, 0, 0); \
            }                                                                   \
            int ts1 = ts0 + CT;                                                 \
            bhf = bhi[(size_t)ts1 * 64 + lane];                                 \
            blf = blo[(size_t)ts1 * 64 + lane];                                 \
            _Pragma("unroll") for (int t = 0; t < 4; ++t) {                     \
                accZ[ct][t] = __builtin_amdgcn_mfma_f32_16x16x32_bf16(ahi[t], bhf, accZ[ct][t], 0, 0, 0); \
                accZ[ct][t] = __builtin_amdgcn_mfma_f32_16x16x32_bf16(alo[t], bhf, accZ[ct][t], 0, 0, 0); \
                accZ[ct][t] = __builtin_amdgcn_mfma_f32_16x16x32_bf16(ahi[t], blf, accZ[ct][t], 0, 0, 0); \
            }                                                                   \
            int ts2 = ts1 + CT;                                                 \
            bhf = bhi[(size_t)ts2 * 64 + lane];                                 \
            blf = blo[(size_t)ts2 * 64 + lane];                                 \
            _Pragma("unroll") for (int t = 0; t < 4; ++t) {                     \
                ACC3[ct][t] = __builtin_amdgcn_mfma_f32_16x16x32_bf16(ahi[t], bhf, ACC3[ct][t], 0, 0, 0); \
                ACC3[ct][t] = __builtin_amdgcn_mfma_f32_16x16x32_bf16(alo[t], bhf, ACC3[ct][t], 0, 0, 0); \
                ACC3[ct][t] = __builtin_amdgcn_mfma_f32_16x16x32_bf16(ahi[t], blf, ACC3[ct][t], 0, 0, 0); \
            }                                                                   \
        }                                                                       \
    }

    GRU_KS_BODY(0, KS / 2, AGhi, AGlo, 0, accN)
    GRU_KS_BODY(KS / 2, KS, Hhi, Hlo, C, accH)
#undef GRU_KS_BODY

    __syncthreads();  // waves share A rows; drain reads before in-place write
#pragma unroll
    for (int ct = 0; ct < CTW; ++ct) {
        int c = (wave * CTW + ct) * 16 + l16;
        float bir = biasI[c], biz = biasI[C + c], bin = biasI[2 * C + c];
        float bhr = biasH[c], bhz = biasH[C + c], bhn = biasH[2 * C + c];
#pragma unroll
        for (int t = 0; t < 4; ++t) {
#pragma unroll
            for (int r = 0; r < 4; ++r) {
                int node = node0 + t * 16 + quad * 4 + r;
                if (node < N) {
                    size_t gi = (size_t)node * C + c;
                    float xo = bf2f(Hhi[gi]) + bf2f(Hlo[gi]);
                    float rv = sigmoid_f(accR[ct][t][r] + bir + bhr);
                    float zv = sigmoid_f(accZ[ct][t][r] + biz + bhz);
                    float nv = tanh_f(accN[ct][t][r] + bin + rv * (accH[ct][t][r] + bhn));
                    put_hl(Hhi, Hlo, gi, (1.f - zv) * nv + zv * xo);
                }
            }
        }
    }
}

// C=32 GRU: 1-A-tile per wave (rows wave-private, no barrier)
__global__ __launch_bounds__(256, 4) void gru_mfma32_kernel(
    unsigned short* __restrict__ Hhi, unsigned short* __restrict__ Hlo,
    const unsigned short* __restrict__ AGhi, const unsigned short* __restrict__ AGlo,
    const unsigned short* __restrict__ BsHi, const unsigned short* __restrict__ BsLo,
    const float* __restrict__ biasI, const float* __restrict__ biasH, int N) {
    constexpr int C = 32;
    constexpr int CT = 2;
    int wave = threadIdx.x >> 6;
    int lane = threadIdx.x & 63;
    int quad = lane >> 4;
    int l16 = lane & 15;
    int node0 = blockIdx.x * 64 + wave * 16;
    int ar = node0 + l16;
    if (ar >= N) ar = N - 1;
    f32x4 accR[CT], accZ[CT], accN[CT], accH[CT];
#pragma unroll
    for (int t = 0; t < CT; ++t) {
        accR[t] = (f32x4){0.f, 0.f, 0.f, 0.f};
        accZ[t] = (f32x4){0.f, 0.f, 0.f, 0.f};
        accN[t] = (f32x4){0.f, 0.f, 0.f, 0.f};
        accH[t] = (f32x4){0.f, 0.f, 0.f, 0.f};
    }
    const short8* bhi = (const short8*)BsHi;
    const short8* blo = (const short8*)BsLo;
    int k0 = quad * 8;
    // ks = 0: AGG half
    {
        short8 ahi = *(const short8*)(AGhi + (size_t)ar * C + k0);
        short8 alo = *(const short8*)(AGlo + (size_t)ar * C + k0);
#pragma unroll
        for (int g = 0; g < 3; ++g) {
            f32x4* acc = g == 0 ? accR : (g == 1 ? accZ : accN);
#pragma unroll
            for (int t = 0; t < CT; ++t) {
                int ts = g * CT + t;
                short8 bhf = bhi[(size_t)ts * 64 + lane];
                short8 blf = blo[(size_t)ts * 64 + lane];
                acc[t] = __builtin_amdgcn_mfma_f32_16x16x32_bf16(ahi, bhf, acc[t], 0, 0, 0);
                acc[t] = __builtin_amdgcn_mfma_f32_16x16x32_bf16(alo, bhf, acc[t], 0, 0, 0);
                acc[t] = __builtin_amdgcn_mfma_f32_16x16x32_bf16(ahi, blf, acc[t], 0, 0, 0);
            }
        }
    }
    // ks = 1: H half
    {
        short8 ahi = *(const short8*)(Hhi + (size_t)ar * C + k0);
        short8 alo = *(const short8*)(Hlo + (size_t)ar * C + k0);
#pragma unroll
        for (int g = 0; g < 3; ++g) {
            f32x4* acc = g == 0 ? accR : (g == 1 ? accZ : accH);
#pragma unroll
            for (int t = 0; t < CT; ++t) {
                int ts = 3 * CT + g * CT + t;
                short8 bhf = bhi[(size_t)ts * 64 + lane];
                short8 blf = blo[(size_t)ts * 64 + lane];
                acc[t] = __builtin_amdgcn_mfma_f32_16x16x32_bf16(ahi, bhf, acc[t], 0, 0, 0);
                acc[t] = __builtin_amdgcn_mfma_f32_16x16x32_bf16(alo, bhf, acc[t], 0, 0, 0);
                acc[t] = __builtin_amdgcn_mfma_f32_16x16x32_bf16(ahi, blf, acc[t], 0, 0, 0);
            }
        }
    }
#pragma unroll
    for (int t = 0; t < CT; ++t) {
        int c = t * 16 + l16;
        float bir = biasI[c], biz = biasI[C + c], bin = biasI[2 * C + c];
        float bhr = biasH[c], bhz = biasH[C + c], bhn = biasH[2 * C + c];
#pragma unroll
        for (int r = 0; r < 4; ++r) {
            int node = node0 + quad * 4 + r;
            if (node < N) {
                size_t gi = (size_t)node * C + c;
                float xo = bf2f(Hhi[gi]) + bf2f(Hlo[gi]);
                float rv = sigmoid_f(accR[t][r] + bir + bhr);
                float zv = sigmoid_f(accZ[t][r] + biz + bhz);
                float nv = tanh_f(accN[t][r] + bin + rv * (accH[t][r] + bhn));
                put_hl(Hhi, Hlo, gi, (1.f - zv) * nv + zv * xo);
            }
        }
    }
}

// ------------------------- epilogues --------------------------------------

__global__ __launch_bounds__(256) void init_x_kernel(
    const float* __restrict__ x, unsigned short* __restrict__ Hhi,
    unsigned short* __restrict__ Hlo, int total) {
    int t = blockIdx.x * 256 + threadIdx.x;
    if (t < total) put_hl(Hhi, Hlo, t, x[t]);
}

template <int Cin, int Cout>
__global__ __launch_bounds__(256) void elu_bn_pad_kernel(
    const unsigned short* __restrict__ Shi, const unsigned short* __restrict__ Slo,
    unsigned short* __restrict__ Dhi, unsigned short* __restrict__ Dlo,
    const float* __restrict__ gamma, const float* __restrict__ beta,
    const float* __restrict__ mean, const float* __restrict__ var, int N) {
    long t = (long)blockIdx.x * 256 + threadIdx.x;
    long total = (long)N * Cout;
    if (t >= total) return;
    int n = (int)(t / Cout);
    int c = (int)(t & (Cout - 1));
    float v = 0.f;
    if (c < Cin) {
        size_t si = (size_t)n * Cin + c;
        float x = bf2f(Shi[si]) + bf2f(Slo[si]);
        x = elu_f(x);
        v = (x - mean[c]) * rsqrtf(var[c] + EPS_BN) * gamma[c] + beta[c];
    }
    put_hl(Dhi, Dlo, t, v);
}

__global__ __launch_bounds__(256) void pool_elu_kernel(
    const unsigned short* __restrict__ Hhi, const unsigned short* __restrict__ Hlo,
    const int* __restrict__ batch, float* __restrict__ G, int N) {
    long t = (long)blockIdx.x * 256 + threadIdx.x;
    if (t >= (long)N * 128) return;
    int n = (int)(t >> 7);
    int c = (int)(t & 127);
    float v = elu_f(bf2f(Hhi[t]) + bf2f(Hlo[t]));
    atomicAdd(&G[batch[n] * 128 + c], v);
}

__global__ __launch_bounds__(256) void fc1_kernel(
    const float* __restrict__ G, const float* __restrict__ W,
    const float* __restrict__ b, float* __restrict__ G2) {
    __shared__ float row[128];
    int g = blockIdx.x;
    int j = threadIdx.x;
    if (j < 128) row[j] = G[g * 128 + j];
    __syncthreads();
    float acc = b[j];
    for (int k = 0; k < 128; ++k) acc += row[k] * W[j * 128 + k];
    G2[g * 256 + j] = elu_f(acc);
}

__global__ __launch_bounds__(64) void fc2_logsoftmax_kernel(
    const float* __restrict__ G2, const float* __restrict__ W,
    const float* __restrict__ b, float* __restrict__ out) {
    __shared__ float row[256];
    __shared__ float logits[10];
    __shared__ float red[2];
    int g = blockIdx.x;
    int tid = threadIdx.x;
    for (int i = tid; i < 256; i += 64) row[i] = G2[g * 256 + i];
    __syncthreads();
    if (tid < 10) {
        float acc = b[tid];
        for (int k = 0; k < 256; ++k) acc += row[k] * W[tid * 256 + k];
        logits[tid] = acc;
    }
    __syncthreads();
    if (tid == 0) {
        float m = -1e30f;
        for (int a = 0; a < 10; ++a) m = fmaxf(m, logits[a]);
        float s = 0.f;
        for (int a = 0; a < 10; ++a) s += expf(logits[a] - m);
        red[0] = m;
        red[1] = logf(s);
    }
    __syncthreads();
    if (tid < 10) out[g * 10 + tid] = logits[tid] - red[0] - red[1];
}

// ---------------------------------------------------------------------------

template <int C>
static void run_conv(unsigned short* Hhi, unsigned short* Hlo,
                     unsigned short* Mhi, unsigned short* Mlo,
                     unsigned short* AGhi, unsigned short* AGlo,
                     unsigned short* WsHi, unsigned short* WsLo,
                     unsigned short* BsHi, unsigned short* BsLo,
                     const float* W, const float* wih, const float* whh,
                     const float* bih, const float* bhh,
                     const int* rowstart, const int* csr_src,
                     int N, int E, hipStream_t stream) {
    swizzle_w_kernel<C><<<(4 * C * C + 255) / 256, 256, 0, stream>>>(W, WsHi, WsLo);
    swizzle_b2_kernel<C><<<(6 * C * C + 255) / 256, 256, 0, stream>>>(wih, whh, BsHi, BsLo);
    int blocks = (N + 63) / 64;
    constexpr int GPB = 256 / (C / 4);
    int gblocks = (N + GPB - 1) / GPB;
    for (int it = 0; it < 4; ++it) {
        if constexpr (C == 32)
            matmul_mfma32_kernel<<<blocks, 256, 0, stream>>>(
                Hhi, Hlo, WsHi + (size_t)it * C * C, WsLo + (size_t)it * C * C, Mhi, Mlo, N);
        else
            matmul_mfma4_kernel<C><<<blocks, 256, 0, stream>>>(
                Hhi, Hlo, WsHi + (size_t)it * C * C, WsLo + (size_t)it * C * C, Mhi, Mlo, N);
        gather_kernel<C><<<gblocks, 256, 0, stream>>>(Mhi, Mlo, rowstart, csr_src, AGhi, AGlo, N);
        if constexpr (C == 32)
            gru_mfma32_kernel<<<blocks, 256, 0, stream>>>(Hhi, Hlo, AGhi, AGlo, BsHi, BsLo, bih, bhh, N);
        else
            gru_mfma4_kernel<C><<<blocks, 256, 0, stream>>>(Hhi, Hlo, AGhi, AGlo, BsHi, BsLo, bih, bhh, N);
    }
}

extern "C" void kernel_launch(void* const* d_in, const int* in_sizes, int n_in,
                              void* d_out, int out_size, void* d_ws, size_t ws_size,
                              hipStream_t stream) {
    const float* x = (const float*)d_in[0];
    const int* ei = (const int*)d_in[1];
    const int* batch = (const int*)d_in[2];
    const float* fc1W = (const float*)d_in[3];
    const float* fc1b = (const float*)d_in[4];
    const float* fc2W = (const float*)d_in[5];
    const float* fc2b = (const float*)d_in[6];
    const float* c1W = (const float*)d_in[7];
    const float* c1wih = (const float*)d_in[8];
    const float* c1whh = (const float*)d_in[9];
    const float* c1bih = (const float*)d_in[10];
    const float* c1bhh = (const float*)d_in[11];
    const float* c2W = (const float*)d_in[12];
    const float* c2wih = (const float*)d_in[13];
    const float* c2whh = (const float*)d_in[14];
    const float* c2bih = (const float*)d_in[15];
    const float* c2bhh = (const float*)d_in[16];
    const float* c3W = (const float*)d_in[17];
    const float* c3wih = (const float*)d_in[18];
    const float* c3whh = (const float*)d_in[19];
    const float* c3bih = (const float*)d_in[20];
    const float* c3bhh = (const float*)d_in[21];
    const float* bn1g = (const float*)d_in[22];
    const float* bn1b = (const float*)d_in[23];
    const float* bn1m = (const float*)d_in[24];
    const float* bn1v = (const float*)d_in[25];
    const float* bn2g = (const float*)d_in[26];
    const float* bn2b = (const float*)d_in[27];
    const float* bn2m = (const float*)d_in[28];
    const float* bn2v = (const float*)d_in[29];

    int N = in_sizes[0] / 32;
    int E = in_sizes[1] / 2;

    const size_t NB = (size_t)N * 128;  // shorts per plane
    unsigned short* PAhi = (unsigned short*)d_ws;  // pair A
    unsigned short* PAlo = PAhi + NB;
    unsigned short* PBhi = PAlo + NB;              // pair B
    unsigned short* PBlo = PBhi + NB;
    unsigned short* AGhi = PBlo + NB;              // AGG pair
    unsigned short* AGlo = AGhi + NB;
    unsigned short* WsHi = AGlo + NB;              // 4*C*C <= 65536
    unsigned short* WsLo = WsHi + 65536;
    unsigned short* BsHi = WsLo + 65536;           // 6*C*C <= 98304
    unsigned short* BsLo = BsHi + 98304;
    float* G = (float*)(BsLo + 98304);
    float* G2 = G + 32768;
    int* deg = (int*)(G2 + 65536);
    int* scanout = deg + N;
    int* rowstart = scanout + N;
    int* writeptr = rowstart + N + 1;
    int* blockSums = writeptr + N;
    int* csr_src = blockSums + 64;

    // ---- build CSR by dst (once; reused by all 12 gathers) ----
    hipMemsetAsync(deg, 0, (size_t)N * sizeof(int), stream);
    int eblocks = (E + 255) / 256;
    hist_kernel<<<eblocks, 256, 0, stream>>>(ei, deg, E);
    int nscan = (N + 1023) / 1024;
    scan1_kernel<<<nscan, 256, 0, stream>>>(deg, scanout, blockSums, N);
    scan2_kernel<<<1, 64, 0, stream>>>(blockSums, nscan);
    scan3_kernel<<<(N + 255) / 256, 256, 0, stream>>>(scanout, blockSums, rowstart, writeptr, N, E);
    fill_kernel<<<eblocks, 256, 0, stream>>>(ei, writeptr, csr_src, E);

    // x -> pair A hi/lo ([N,32])
    init_x_kernel<<<(N * 32 + 255) / 256, 256, 0, stream>>>(x, PAhi, PAlo, N * 32);

    // conv1 (C=32): state pair A; M planes alias pair B region
    run_conv<32>(PAhi, PAlo, PBhi, PBlo, AGhi, AGlo, WsHi, WsLo, BsHi, BsLo,
                 c1W, c1wih, c1whh, c1bih, c1bhh, rowstart, csr_src, N, E, stream);
    elu_bn_pad_kernel<32, 64><<<(int)(((long)N * 64 + 255) / 256), 256, 0, stream>>>(
        PAhi, PAlo, PBhi, PBlo, bn1g, bn1b, bn1m, bn1v, N);

    // conv2 (C=64): state pair B; M planes alias pair A region
    run_conv<64>(PBhi, PBlo, PAhi, PAlo, AGhi, AGlo, WsHi, WsLo, BsHi, BsLo,
                 c2W, c2wih, c2whh, c2bih, c2bhh, rowstart, csr_src, N, E, stream);
    elu_bn_pad_kernel<64, 128><<<(int)(((long)N * 128 + 255) / 256), 256, 0, stream>>>(
        PBhi, PBlo, PAhi, PAlo, bn2g, bn2b, bn2m, bn2v, N);

    // conv3 (C=128): state pair A; M planes alias pair B region
    run_conv<128>(PAhi, PAlo, PBhi, PBlo, AGhi, AGlo, WsHi, WsLo, BsHi, BsLo,
                  c3W, c3wih, c3whh, c3bih, c3bhh, rowstart, csr_src, N, E, stream);

    // pool (reads pair A, stride 128)
    hipMemsetAsync(G, 0, 256 * 128 * sizeof(float), stream);
    pool_elu_kernel<<<(int)(((long)N * 128 + 255) / 256), 256, 0, stream>>>(
        PAhi, PAlo, batch, G, N);

    fc1_kernel<<<256, 256, 0, stream>>>(G, fc1W, fc1b, G2);
    fc2_logsoftmax_kernel<<<256, 64, 0, stream>>>(G2, fc2W, fc2b, (float*)d_out);
}

// Round 6
// 1338.384 us; speedup vs baseline: 2.8407x; 1.0679x over previous
//
#include <hip/hip_runtime.h>
#include <math.h>

// ---------------------------------------------------------------------------
// GNN: 3x GatedGraphConv (C=32,64,128; 4 inner layers each) + BN + pool + MLP
// Round 6: algebraic reordering agg = gather(x) @ W  =>  gi = gather(x) @ Wc,
// Wc = W @ wih^T precomputed per layer (matmul kernel + M buffer eliminated).
// GRU is out-of-place (state ping-pong) so column-split blocks can't race.
// Split-bf16 hi/lo planes everywhere:  A*B ~= Ahi*Bhi + Alo*Bhi + Ahi*Blo.
// ---------------------------------------------------------------------------

#define EPS_BN 1e-5f

typedef short short8 __attribute__((ext_vector_type(8)));
typedef float f32x4 __attribute__((ext_vector_type(4)));

__device__ __forceinline__ float elu_f(float v) {
    return v > 0.f ? v : expm1f(v);
}
__device__ __forceinline__ float sigmoid_f(float v) {
    return 1.f / (1.f + __expf(-v));
}
__device__ __forceinline__ float tanh_f(float v) {
    float e = __expf(2.f * v);
    return 1.f - 2.f / (e + 1.f);
}
__device__ __forceinline__ unsigned short f2bf(float f) {
    unsigned u = __float_as_uint(f);
    unsigned r = (u + 0x7FFF + ((u >> 16) & 1)) >> 16;
    return (unsigned short)r;
}
__device__ __forceinline__ float bf2f(unsigned short b) {
    return __uint_as_float(((unsigned)b) << 16);
}
__device__ __forceinline__ void put_hl(unsigned short* __restrict__ hi,
                                       unsigned short* __restrict__ lo,
                                       size_t idx, float v) {
    unsigned short h = f2bf(v);
    hi[idx] = h;
    lo[idx] = f2bf(v - bf2f(h));
}

// ------------------------- CSR construction -------------------------------

__global__ __launch_bounds__(256) void hist_kernel(
    const int* __restrict__ ei, int* __restrict__ deg, int E) {
    int e = blockIdx.x * 256 + threadIdx.x;
    if (e < E) atomicAdd(&deg[ei[E + e]], 1);
}

__global__ __launch_bounds__(256) void scan1_kernel(
    const int* __restrict__ deg, int* __restrict__ out,
    int* __restrict__ blockSums, int N) {
    __shared__ int sdata[256];
    int b = blockIdx.x, t = threadIdx.x;
    int base = b * 1024 + t * 4;
    int v[4], s = 0;
#pragma unroll
    for (int i = 0; i < 4; ++i) {
        v[i] = (base + i < N) ? deg[base + i] : 0;
        s += v[i];
    }
    sdata[t] = s;
    __syncthreads();
    for (int off = 1; off < 256; off <<= 1) {
        int x = (t >= off) ? sdata[t - off] : 0;
        __syncthreads();
        sdata[t] += x;
        __syncthreads();
    }
    int run = sdata[t] - s;
#pragma unroll
    for (int i = 0; i < 4; ++i) {
        if (base + i < N) out[base + i] = run;
        run += v[i];
    }
    if (t == 255) blockSums[b] = sdata[255];
}

__global__ void scan2_kernel(int* blockSums, int nb) {
    if (threadIdx.x == 0 && blockIdx.x == 0) {
        int run = 0;
        for (int i = 0; i < nb; ++i) {
            int v = blockSums[i];
            blockSums[i] = run;
            run += v;
        }
    }
}

__global__ __launch_bounds__(256) void scan3_kernel(
    const int* __restrict__ out, const int* __restrict__ blockSums,
    int* __restrict__ rowstart, int* __restrict__ writeptr, int N, int E) {
    int i = blockIdx.x * 256 + threadIdx.x;
    if (i < N) {
        int v = out[i] + blockSums[i >> 10];
        rowstart[i] = v;
        writeptr[i] = v;
    }
    if (i == 0) rowstart[N] = E;
}

__global__ __launch_bounds__(256) void fill_kernel(
    const int* __restrict__ ei, int* __restrict__ writeptr,
    int* __restrict__ csr_src, int E) {
    int e = blockIdx.x * 256 + threadIdx.x;
    if (e < E) {
        int d = ei[E + e];
        int p = atomicAdd(&writeptr[d], 1);
        csr_src[p] = ei[e];
    }
}

// ------------------------- Wc = W[l] @ wih^T ------------------------------
// W: [4,C,C], wih: [3C,C]  ->  Wc: [4, C, 3C] fp32
// Wc[l][k][row] = sum_t W[l][k][t] * wih[row][t]

template <int C>
__global__ __launch_bounds__(256) void wc_kernel(
    const float* __restrict__ W, const float* __restrict__ wih,
    float* __restrict__ Wc) {
    int idx = blockIdx.x * 256 + threadIdx.x;
    if (idx >= 4 * C * 3 * C) return;
    int l = idx / (C * 3 * C);
    int r = idx % (C * 3 * C);
    int k = r / (3 * C);
    int row = r % (3 * C);
    const float* wrow = W + ((size_t)l * C + k) * C;
    const float* irow = wih + (size_t)row * C;
    float acc = 0.f;
#pragma unroll 4
    for (int t = 0; t < C; ++t) acc += wrow[t] * irow[t];
    Wc[idx] = acc;
}

// ------------------------- B2 swizzle (hi/lo, all 4 layers) ---------------
// mfma_f32_16x16x32_bf16 layouts:
//   A[m][k]: m = lane&15, k = (lane>>4)*8 + j
//   B[k][n]: n = lane&15, k = (lane>>4)*8 + j
//   C/D:     col = lane&15, row = (lane>>4)*4 + reg
// GRU concat-B: K = 2C (k<C: Wc_l on S; k>=C: whh on X).
// tslot per ks: [0,CT): r ; [CT,2CT): z ; [2CT,3CT): k<C ? in : hn

template <int C>
__global__ __launch_bounds__(256) void swizzle_b2_kernel(
    const float* __restrict__ Wc, const float* __restrict__ whh,
    unsigned short* __restrict__ BsHi, unsigned short* __restrict__ BsLo) {
    constexpr int CT = C / 16;
    int idx = blockIdx.x * 256 + threadIdx.x;
    if (idx >= 4 * 6 * C * C) return;
    int l = idx / (6 * C * C);
    int r0 = idx % (6 * C * C);
    int j = r0 & 7;
    int lane = (r0 >> 3) & 63;
    int rest = r0 >> 9;
    int tslot = rest % (3 * CT);
    int ks = rest / (3 * CT);
    int k = ks * 32 + (lane >> 4) * 8 + j;
    int g = tslot / CT;
    int lt = tslot % CT;
    int c = lt * 16 + (lane & 15);
    int row = g * C + c;
    float v = (k < C) ? Wc[((size_t)l * C + k) * 3 * C + row]
                      : whh[(size_t)row * C + (k - C)];
    unsigned short h = f2bf(v);
    BsHi[idx] = h;
    BsLo[idx] = f2bf(v - bf2f(h));
}

// ------------------------- gather: S[d] = sum X[src] ----------------------

template <int C>
__global__ __launch_bounds__(256) void gather_kernel(
    const unsigned short* __restrict__ Xhi, const unsigned short* __restrict__ Xlo,
    const int* __restrict__ rowstart, const int* __restrict__ csr_src,
    unsigned short* __restrict__ Shi, unsigned short* __restrict__ Slo, int N) {
    constexpr int LPG = C / 4;
    constexpr int GPB = 256 / LPG;
    int lane = threadIdx.x % LPG;
    int grp = threadIdx.x / LPG;
    int d = blockIdx.x * GPB + grp;
    if (d >= N) return;
    int p = rowstart[d];
    int p1 = rowstart[d + 1];
    float a0 = 0.f, a1 = 0.f, a2 = 0.f, a3 = 0.f;
    for (; p < p1; ++p) {
        int s = csr_src[p];
        ushort4 vh = ((const ushort4*)(Xhi + (size_t)s * C))[lane];
        ushort4 vl = ((const ushort4*)(Xlo + (size_t)s * C))[lane];
        a0 += bf2f(vh.x) + bf2f(vl.x);
        a1 += bf2f(vh.y) + bf2f(vl.y);
        a2 += bf2f(vh.z) + bf2f(vl.z);
        a3 += bf2f(vh.w) + bf2f(vl.w);
    }
    size_t base = (size_t)d * C + lane * 4;
    put_hl(Shi, Slo, base + 0, a0);
    put_hl(Shi, Slo, base + 1, a1);
    put_hl(Shi, Slo, base + 2, a2);
    put_hl(Shi, Slo, base + 3, a3);
}

// ------------------------- GRU cell (C = 64 / 128) ------------------------
// Block = 4 waves = 64 nodes (4 A-tiles). Column-split factor CS: grid is
// nb*CS blocks; wave w of split cs owns column tile wslot = cs*4+w of every
// gate (wslot in [0, CT)). Out-of-place: reads Hin/S, writes Hout.

template <int C, int CS>
__global__ __launch_bounds__(256, 3) void gru_mfma_kernel(
    const unsigned short* __restrict__ HinHi, const unsigned short* __restrict__ HinLo,
    unsigned short* __restrict__ HoutHi, unsigned short* __restrict__ HoutLo,
    const unsigned short* __restrict__ Shi, const unsigned short* __restrict__ Slo,
    const unsigned short* __restrict__ BsHi, const unsigned short* __restrict__ BsLo,
    const float* __restrict__ biasI, const float* __restrict__ biasH,
    int N, int nb) {
    constexpr int CT = C / 16;
    constexpr int KS = C / 16;  // = 2C/32 k-steps
    int bx = blockIdx.x % nb;
    int cs = blockIdx.x / nb;
    int wave = threadIdx.x >> 6;
    int lane = threadIdx.x & 63;
    int quad = lane >> 4;
    int l16 = lane & 15;
    int wslot = cs * 4 + wave;  // column tile of each gate (in [0, CT))
    int node0 = bx * 64;
    int arow[4];
#pragma unroll
    for (int t = 0; t < 4; ++t) {
        int r = node0 + t * 16 + l16;
        arow[t] = r < N ? r : N - 1;
    }
    f32x4 accR[4], accZ[4], accN[4], accH[4];
#pragma unroll
    for (int t = 0; t < 4; ++t) {
        accR[t] = (f32x4){0.f, 0.f, 0.f, 0.f};
        accZ[t] = (f32x4){0.f, 0.f, 0.f, 0.f};
        accN[t] = (f32x4){0.f, 0.f, 0.f, 0.f};
        accH[t] = (f32x4){0.f, 0.f, 0.f, 0.f};
    }
    const short8* bhi = (const short8*)BsHi;
    const short8* blo = (const short8*)BsLo;

#define GRU_HALF(KS0, KS1, SRCHI, SRCLO, KOFF, ACC3)                            \
    for (int ks = (KS0); ks < (KS1); ++ks) {                                    \
        int k0 = ks * 32 + quad * 8 - (KOFF);                                   \
        short8 ahi[4], alo[4];                                                  \
        _Pragma("unroll") for (int t = 0; t < 4; ++t) {                         \
            ahi[t] = *(const short8*)((SRCHI) + (size_t)arow[t] * C + k0);      \
            alo[t] = *(const short8*)((SRCLO) + (size_t)arow[t] * C + k0);      \
        }                                                                       \
        int ts = ks * 3 * CT + wslot;                                           \
        short8 bhf = bhi[(size_t)ts * 64 + lane];                               \
        short8 blf = blo[(size_t)ts * 64 + lane];                               \
        _Pragma("unroll") for (int t = 0; t < 4; ++t) {                         \
            accR[t] = __builtin_amdgcn_mfma_f32_16x16x32_bf16(ahi[t], bhf, accR[t], 0, 0, 0); \
            accR[t] = __builtin_amdgcn_mfma_f32_16x16x32_bf16(alo[t], bhf, accR[t], 0, 0, 0); \
            accR[t] = __builtin_amdgcn_mfma_f32_16x16x32_bf16(ahi[t], blf, accR[t], 0, 0, 0); \
        }                                                                       \
        bhf = bhi[(size_t)(ts + CT) * 64 + lane];                               \
        blf = blo[(size_t)(ts + CT) * 64 + lane];                               \
        _Pragma("unroll") for (int t = 0; t < 4; ++t) {                         \
            accZ[t] = __builtin_amdgcn_mfma_f32_16x16x32_bf16(ahi[t], bhf, accZ[t], 0, 0, 0); \
            accZ[t] = __builtin_amdgcn_mfma_f32_16x16x32_bf16(alo[t], bhf, accZ[t], 0, 0, 0); \
            accZ[t] = __builtin_amdgcn_mfma_f32_16x16x32_bf16(ahi[t], blf, accZ[t], 0, 0, 0); \
        }                                                                       \
        bhf = bhi[(size_t)(ts + 2 * CT) * 64 + lane];                           \
        blf = blo[(size_t)(ts + 2 * CT) * 64 + lane];                           \
        _Pragma("unroll") for (int t = 0; t < 4; ++t) {                         \
            ACC3[t] = __builtin_amdgcn_mfma_f32_16x16x32_bf16(ahi[t], bhf, ACC3[t], 0, 0, 0); \
            ACC3[t] = __builtin_amdgcn_mfma_f32_16x16x32_bf16(alo[t], bhf, ACC3[t], 0, 0, 0); \
            ACC3[t] = __builtin_amdgcn_mfma_f32_16x16x32_bf16(ahi[t], blf, ACC3[t], 0, 0, 0); \
        }                                                                       \
    }

    GRU_HALF(0, KS / 2, Shi, Slo, 0, accN)
    GRU_HALF(KS / 2, KS, HinHi, HinLo, C, accH)
#undef GRU_HALF

    int c = wslot * 16 + l16;
    float bir = biasI[c], biz = biasI[C + c], bin = biasI[2 * C + c];
    float bhr = biasH[c], bhz = biasH[C + c], bhn = biasH[2 * C + c];
#pragma unroll
    for (int t = 0; t < 4; ++t) {
#pragma unroll
        for (int r = 0; r < 4; ++r) {
            int node = node0 + t * 16 + quad * 4 + r;
            if (node < N) {
                size_t gi = (size_t)node * C + c;
                float xo = bf2f(HinHi[gi]) + bf2f(HinLo[gi]);
                float rv = sigmoid_f(accR[t][r] + bir + bhr);
                float zv = sigmoid_f(accZ[t][r] + biz + bhz);
                float nv = tanh_f(accN[t][r] + bin + rv * (accH[t][r] + bhn));
                put_hl(HoutHi, HoutLo, gi, (1.f - zv) * nv + zv * xo);
            }
        }
    }
}

// C=32 GRU: 1 A-tile per wave, out-of-place
__global__ __launch_bounds__(256, 4) void gru32_kernel(
    const unsigned short* __restrict__ HinHi, const unsigned short* __restrict__ HinLo,
    unsigned short* __restrict__ HoutHi, unsigned short* __restrict__ HoutLo,
    const unsigned short* __restrict__ Shi, const unsigned short* __restrict__ Slo,
    const unsigned short* __restrict__ BsHi, const unsigned short* __restrict__ BsLo,
    const float* __restrict__ biasI, const float* __restrict__ biasH, int N) {
    constexpr int C = 32;
    constexpr int CT = 2;
    int wave = threadIdx.x >> 6;
    int lane = threadIdx.x & 63;
    int quad = lane >> 4;
    int l16 = lane & 15;
    int node0 = blockIdx.x * 64 + wave * 16;
    int ar = node0 + l16;
    if (ar >= N) ar = N - 1;
    f32x4 accR[CT], accZ[CT], accN[CT], accH[CT];
#pragma unroll
    for (int t = 0; t < CT; ++t) {
        accR[t] = (f32x4){0.f, 0.f, 0.f, 0.f};
        accZ[t] = (f32x4){0.f, 0.f, 0.f, 0.f};
        accN[t] = (f32x4){0.f, 0.f, 0.f, 0.f};
        accH[t] = (f32x4){0.f, 0.f, 0.f, 0.f};
    }
    const short8* bhi = (const short8*)BsHi;
    const short8* blo = (const short8*)BsLo;
    int k0 = quad * 8;
    {  // ks = 0: S half
        short8 ahi = *(const short8*)(Shi + (size_t)ar * C + k0);
        short8 alo = *(const short8*)(Slo + (size_t)ar * C + k0);
#pragma unroll
        for (int g = 0; g < 3; ++g) {
            f32x4* acc = g == 0 ? accR : (g == 1 ? accZ : accN);
#pragma unroll
            for (int t = 0; t < CT; ++t) {
                int ts = g * CT + t;
                short8 bhf = bhi[(size_t)ts * 64 + lane];
                short8 blf = blo[(size_t)ts * 64 + lane];
                acc[t] = __builtin_amdgcn_mfma_f32_16x16x32_bf16(ahi, bhf, acc[t], 0, 0, 0);
                acc[t] = __builtin_amdgcn_mfma_f32_16x16x32_bf16(alo, bhf, acc[t], 0, 0, 0);
                acc[t] = __builtin_amdgcn_mfma_f32_16x16x32_bf16(ahi, blf, acc[t], 0, 0, 0);
            }
        }
    }
    {  // ks = 1: H half
        short8 ahi = *(const short8*)(HinHi + (size_t)ar * C + k0);
        short8 alo = *(const short8*)(HinLo + (size_t)ar * C + k0);
#pragma unroll
        for (int g = 0; g < 3; ++g) {
            f32x4* acc = g == 0 ? accR : (g == 1 ? accZ : accH);
#pragma unroll
            for (int t = 0; t < CT; ++t) {
                int ts = 3 * CT + g * CT + t;
                short8 bhf = bhi[(size_t)ts * 64 + lane];
                short8 blf = blo[(size_t)ts * 64 + lane];
                acc[t] = __builtin_amdgcn_mfma_f32_16x16x32_bf16(ahi, bhf, acc[t], 0, 0, 0);
                acc[t] = __builtin_amdgcn_mfma_f32_16x16x32_bf16(alo, bhf, acc[t], 0, 0, 0);
                acc[t] = __builtin_amdgcn_mfma_f32_16x16x32_bf16(ahi, blf, acc[t], 0, 0, 0);
            }
        }
    }
#pragma unroll
    for (int t = 0; t < CT; ++t) {
        int c = t * 16 + l16;
        float bir = biasI[c], biz = biasI[C + c], bin = biasI[2 * C + c];
        float bhr = biasH[c], bhz = biasH[C + c], bhn = biasH[2 * C + c];
#pragma unroll
        for (int r = 0; r < 4; ++r) {
            int node = node0 + quad * 4 + r;
            if (node < N) {
                size_t gi = (size_t)node * C + c;
                float xo = bf2f(HinHi[gi]) + bf2f(HinLo[gi]);
                float rv = sigmoid_f(accR[t][r] + bir + bhr);
                float zv = sigmoid_f(accZ[t][r] + biz + bhz);
                float nv = tanh_f(accN[t][r] + bin + rv * (accH[t][r] + bhn));
                put_hl(HoutHi, HoutLo, gi, (1.f - zv) * nv + zv * xo);
            }
        }
    }
}

// ------------------------- epilogues --------------------------------------

__global__ __launch_bounds__(256) void init_x_kernel(
    const float* __restrict__ x, unsigned short* __restrict__ Hhi,
    unsigned short* __restrict__ Hlo, int total) {
    int t = blockIdx.x * 256 + threadIdx.x;
    if (t < total) put_hl(Hhi, Hlo, t, x[t]);
}

template <int Cin, int Cout>
__global__ __launch_bounds__(256) void elu_bn_pad_kernel(
    const unsigned short* __restrict__ Shi, const unsigned short* __restrict__ Slo,
    unsigned short* __restrict__ Dhi, unsigned short* __restrict__ Dlo,
    const float* __restrict__ gamma, const float* __restrict__ beta,
    const float* __restrict__ mean, const float* __restrict__ var, int N) {
    long t = (long)blockIdx.x * 256 + threadIdx.x;
    long total = (long)N * Cout;
    if (t >= total) return;
    int n = (int)(t / Cout);
    int c = (int)(t & (Cout - 1));
    float v = 0.f;
    if (c < Cin) {
        size_t si = (size_t)n * Cin + c;
        float x = bf2f(Shi[si]) + bf2f(Slo[si]);
        x = elu_f(x);
        v = (x - mean[c]) * rsqrtf(var[c] + EPS_BN) * gamma[c] + beta[c];
    }
    put_hl(Dhi, Dlo, t, v);
}

__global__ __launch_bounds__(256) void pool_elu_kernel(
    const unsigned short* __restrict__ Hhi, const unsigned short* __restrict__ Hlo,
    const int* __restrict__ batch, float* __restrict__ G, int N) {
    long t = (long)blockIdx.x * 256 + threadIdx.x;
    if (t >= (long)N * 128) return;
    int n = (int)(t >> 7);
    int c = (int)(t & 127);
    float v = elu_f(bf2f(Hhi[t]) + bf2f(Hlo[t]));
    atomicAdd(&G[batch[n] * 128 + c], v);
}

__global__ __launch_bounds__(256) void fc1_kernel(
    const float* __restrict__ G, const float* __restrict__ W,
    const float* __restrict__ b, float* __restrict__ G2) {
    __shared__ float row[128];
    int g = blockIdx.x;
    int j = threadIdx.x;
    if (j < 128) row[j] = G[g * 128 + j];
    __syncthreads();
    float acc = b[j];
    for (int k = 0; k < 128; ++k) acc += row[k] * W[j * 128 + k];
    G2[g * 256 + j] = elu_f(acc);
}

__global__ __launch_bounds__(64) void fc2_logsoftmax_kernel(
    const float* __restrict__ G2, const float* __restrict__ W,
    const float* __restrict__ b, float* __restrict__ out) {
    __shared__ float row[256];
    __shared__ float logits[10];
    __shared__ float red[2];
    int g = blockIdx.x;
    int tid = threadIdx.x;
    for (int i = tid; i < 256; i += 64) row[i] = G2[g * 256 + i];
    __syncthreads();
    if (tid < 10) {
        float acc = b[tid];
        for (int k = 0; k < 256; ++k) acc += row[k] * W[tid * 256 + k];
        logits[tid] = acc;
    }
    __syncthreads();
    if (tid == 0) {
        float m = -1e30f;
        for (int a = 0; a < 10; ++a) m = fmaxf(m, logits[a]);
        float s = 0.f;
        for (int a = 0; a < 10; ++a) s += expf(logits[a] - m);
        red[0] = m;
        red[1] = logf(s);
    }
    __syncthreads();
    if (tid < 10) out[g * 10 + tid] = logits[tid] - red[0] - red[1];
}

// ---------------------------------------------------------------------------

template <int C>
static void run_conv(unsigned short* Ahi, unsigned short* Alo,
                     unsigned short* Bhi, unsigned short* Blo,
                     unsigned short* Shi, unsigned short* Slo,
                     float* Wc, unsigned short* BsHi, unsigned short* BsLo,
                     const float* W, const float* wih, const float* whh,
                     const float* bih, const float* bhh,
                     const int* rowstart, const int* csr_src,
                     int N, int E, hipStream_t stream) {
    wc_kernel<C><<<(4 * C * 3 * C + 255) / 256, 256, 0, stream>>>(W, wih, Wc);
    swizzle_b2_kernel<C><<<(4 * 6 * C * C + 255) / 256, 256, 0, stream>>>(Wc, whh, BsHi, BsLo);
    int nb = (N + 63) / 64;
    constexpr int CS = (C == 128) ? 2 : 1;
    constexpr int GPB = 256 / (C / 4);
    int gblocks = (N + GPB - 1) / GPB;
    unsigned short *inHi = Ahi, *inLo = Alo, *outHi = Bhi, *outLo = Blo;
    for (int it = 0; it < 4; ++it) {
        gather_kernel<C><<<gblocks, 256, 0, stream>>>(inHi, inLo, rowstart, csr_src, Shi, Slo, N);
        const unsigned short* bs_h = BsHi + (size_t)it * 6 * C * C;
        const unsigned short* bs_l = BsLo + (size_t)it * 6 * C * C;
        if constexpr (C == 32)
            gru32_kernel<<<nb, 256, 0, stream>>>(
                inHi, inLo, outHi, outLo, Shi, Slo, bs_h, bs_l, bih, bhh, N);
        else
            gru_mfma_kernel<C, CS><<<nb * CS, 256, 0, stream>>>(
                inHi, inLo, outHi, outLo, Shi, Slo, bs_h, bs_l, bih, bhh, N, nb);
        unsigned short* tp;
        tp = inHi; inHi = outHi; outHi = tp;
        tp = inLo; inLo = outLo; outLo = tp;
    }
    // 4 iterations (even) -> final state back in (Ahi, Alo)
}

extern "C" void kernel_launch(void* const* d_in, const int* in_sizes, int n_in,
                              void* d_out, int out_size, void* d_ws, size_t ws_size,
                              hipStream_t stream) {
    const float* x = (const float*)d_in[0];
    const int* ei = (const int*)d_in[1];
    const int* batch = (const int*)d_in[2];
    const float* fc1W = (const float*)d_in[3];
    const float* fc1b = (const float*)d_in[4];
    const float* fc2W = (const float*)d_in[5];
    const float* fc2b = (const float*)d_in[6];
    const float* c1W = (const float*)d_in[7];
    const float* c1wih = (const float*)d_in[8];
    const float* c1whh = (const float*)d_in[9];
    const float* c1bih = (const float*)d_in[10];
    const float* c1bhh = (const float*)d_in[11];
    const float* c2W = (const float*)d_in[12];
    const float* c2wih = (const float*)d_in[13];
    const float* c2whh = (const float*)d_in[14];
    const float* c2bih = (const float*)d_in[15];
    const float* c2bhh = (const float*)d_in[16];
    const float* c3W = (const float*)d_in[17];
    const float* c3wih = (const float*)d_in[18];
    const float* c3whh = (const float*)d_in[19];
    const float* c3bih = (const float*)d_in[20];
    const float* c3bhh = (const float*)d_in[21];
    const float* bn1g = (const float*)d_in[22];
    const float* bn1b = (const float*)d_in[23];
    const float* bn1m = (const float*)d_in[24];
    const float* bn1v = (const float*)d_in[25];
    const float* bn2g = (const float*)d_in[26];
    const float* bn2b = (const float*)d_in[27];
    const float* bn2m = (const float*)d_in[28];
    const float* bn2v = (const float*)d_in[29];

    int N = in_sizes[0] / 32;
    int E = in_sizes[1] / 2;

    const size_t NB = (size_t)N * 128;  // shorts per plane
    unsigned short* PAhi = (unsigned short*)d_ws;  // state pair A
    unsigned short* PAlo = PAhi + NB;
    unsigned short* PBhi = PAlo + NB;              // state pair B (ping-pong)
    unsigned short* PBlo = PBhi + NB;
    unsigned short* Shi = PBlo + NB;               // gathered-S pair
    unsigned short* Slo = Shi + NB;
    unsigned short* BsHi = Slo + NB;               // 4 layers x 6*C*C <= 393216
    unsigned short* BsLo = BsHi + 393216;
    float* Wc = (float*)(BsLo + 393216);           // 4*C*3C <= 196608 floats
    float* G = Wc + 196608;
    float* G2 = G + 32768;
    int* deg = (int*)(G2 + 65536);
    int* scanout = deg + N;
    int* rowstart = scanout + N;
    int* writeptr = rowstart + N + 1;
    int* blockSums = writeptr + N;
    int* csr_src = blockSums + 64;

    // ---- build CSR by dst (once; reused by all 12 gathers) ----
    hipMemsetAsync(deg, 0, (size_t)N * sizeof(int), stream);
    int eblocks = (E + 255) / 256;
    hist_kernel<<<eblocks, 256, 0, stream>>>(ei, deg, E);
    int nscan = (N + 1023) / 1024;
    scan1_kernel<<<nscan, 256, 0, stream>>>(deg, scanout, blockSums, N);
    scan2_kernel<<<1, 64, 0, stream>>>(blockSums, nscan);
    scan3_kernel<<<(N + 255) / 256, 256, 0, stream>>>(scanout, blockSums, rowstart, writeptr, N, E);
    fill_kernel<<<eblocks, 256, 0, stream>>>(ei, writeptr, csr_src, E);

    // x -> pair A hi/lo ([N,32])
    init_x_kernel<<<(N * 32 + 255) / 256, 256, 0, stream>>>(x, PAhi, PAlo, N * 32);

    // conv1 (C=32): state PA, ping-pong with PB
    run_conv<32>(PAhi, PAlo, PBhi, PBlo, Shi, Slo, Wc, BsHi, BsLo,
                 c1W, c1wih, c1whh, c1bih, c1bhh, rowstart, csr_src, N, E, stream);
    elu_bn_pad_kernel<32, 64><<<(int)(((long)N * 64 + 255) / 256), 256, 0, stream>>>(
        PAhi, PAlo, PBhi, PBlo, bn1g, bn1b, bn1m, bn1v, N);

    // conv2 (C=64): state PB, ping-pong with PA
    run_conv<64>(PBhi, PBlo, PAhi, PAlo, Shi, Slo, Wc, BsHi, BsLo,
                 c2W, c2wih, c2whh, c2bih, c2bhh, rowstart, csr_src, N, E, stream);
    elu_bn_pad_kernel<64, 128><<<(int)(((long)N * 128 + 255) / 256), 256, 0, stream>>>(
        PBhi, PBlo, PAhi, PAlo, bn2g, bn2b, bn2m, bn2v, N);

    // conv3 (C=128): state PA, ping-pong with PB
    run_conv<128>(PAhi, PAlo, PBhi, PBlo, Shi, Slo, Wc, BsHi, BsLo,
                  c3W, c3wih, c3whh, c3bih, c3bhh, rowstart, csr_src, N, E, stream);

    // pool (reads pair A, stride 128)
    hipMemsetAsync(G, 0, 256 * 128 * sizeof(float), stream);
    pool_elu_kernel<<<(int)(((long)N * 128 + 255) / 256), 256, 0, stream>>>(
        PAhi, PAlo, batch, G, N);

    fc1_kernel<<<256, 256, 0, stream>>>(G, fc1W, fc1b, G2);
    fc2_logsoftmax_kernel<<<256, 64, 0, stream>>>(G2, fc2W, fc2b, (float*)d_out);
}